// Round 1
// baseline (4452.386 us; speedup 1.0000x reference)
//
#include <hip/hip_runtime.h>
#include <hip/hip_bf16.h>

#define NN 2048
#define EE 32768
#define DND 512
#define DED 512
#define NH 8
#define HD 64
#define NEGF (-1e30f)
#define BN_SCALE 0.9999950000374997f  // 1/sqrt(1+1e-5)

static __device__ __forceinline__ float4 ld4(const float* p) {
    return *reinterpret_cast<const float4*>(p);
}

// ---------------- setup kernels ----------------

__global__ __launch_bounds__(256) void init_table_k(int* __restrict__ t) {
    int i = blockIdx.x * 256 + threadIdx.x;
    t[i] = -1;
}

__global__ __launch_bounds__(256) void fill_table_k(const int* __restrict__ ei, int* __restrict__ t) {
    int e = blockIdx.x * 256 + threadIdx.x;
    if (e < EE) t[(size_t)ei[e] * NN + ei[EE + e]] = e;
}

__global__ __launch_bounds__(256) void build_rev_k(const int* __restrict__ ei, const int* __restrict__ t,
                                                   int* __restrict__ rev) {
    int e = blockIdx.x * 256 + threadIdx.x;
    if (e < EE) rev[e] = t[(size_t)ei[EE + e] * NN + ei[e]];
}

__global__ __launch_bounds__(256) void build_mask_k(const int* __restrict__ t, const float* __restrict__ pos,
                                                    float* __restrict__ mask) {
    int idx = blockIdx.x * 256 + threadIdx.x;
    int i = idx >> 11, j = idx & (NN - 1);
    float v;
    if (i == j) {
        v = 1.0f;
    } else if (t[idx] >= 0 || t[(size_t)j * NN + i] >= 0) {
        float dx = pos[i * 3 + 0] - pos[j * 3 + 0];
        float dy = pos[i * 3 + 1] - pos[j * 3 + 1];
        float dz = pos[i * 3 + 2] - pos[j * 3 + 2];
        v = 1.0f / (sqrtf(dx * dx + dy * dy + dz * dz) + 1e-6f);
    } else {
        v = NEGF;
    }
    mask[idx] = v;
}

// ---------------- GEMM: C[M,Nc] = epi(Agather[M,K] @ B[Nc,K]^T + bias) ----------------
// MODE 0: A plain row-major M x K
// MODE 1: A = [nf[src], ef, ef[rev]|0, nf[dst]]  (K = 2048), g0=nf, g1=ef
// MODE 2: A = [xupd, subj+obj]                   (K = 1024), g0=xupd, g1=subj, g2=obj
// EPI 0: +bias     EPI 1: relu(+bias)     EPI 2: relu((+bias)*BN_SCALE*eg + eb)
template <int MODE, int EPI>
__global__ __launch_bounds__(256) void gemm_k(
    const float* __restrict__ A, const float* __restrict__ B,
    const float* __restrict__ bias, float* __restrict__ C,
    int M, int Nc, int K,
    const float* __restrict__ g0, const float* __restrict__ g1, const float* __restrict__ g2,
    const int* __restrict__ srcv, const int* __restrict__ dstv, const int* __restrict__ revv,
    const float* __restrict__ eg, const float* __restrict__ eb)
{
    __shared__ float As[16][128];
    __shared__ float Bs[16][128];
    const int tid = threadIdx.x;
    const int bm = blockIdx.x * 128, bn = blockIdx.y * 128;
    const int lr = tid >> 1;        // 0..127
    const int lk = (tid & 1) * 8;   // 0 or 8
    const int ty = tid >> 4, tx = tid & 15;
    const int arow = bm + lr;
    const int brow = bn + lr;
    int asrc = 0, adst = 0, arev = -1;
    const float* ap = nullptr;
    if (MODE == 0) ap = A + (size_t)arow * K;
    else if (MODE == 1) { asrc = srcv[arow]; adst = dstv[arow]; arev = revv[arow]; }
    float acc[8][8] = {};
    for (int k0 = 0; k0 < K; k0 += 16) {
#pragma unroll
        for (int half = 0; half < 2; ++half) {
            const int kk = k0 + lk + half * 4;
            float4 av;
            if (MODE == 0) {
                av = ld4(ap + kk);
            } else if (MODE == 1) {
                if (kk < DND)                 av = ld4(g0 + (size_t)asrc * DND + kk);
                else if (kk < DND + DED)      av = ld4(g1 + (size_t)arow * DED + (kk - DND));
                else if (kk < DND + 2 * DED)  av = (arev >= 0) ? ld4(g1 + (size_t)arev * DED + (kk - DND - DED))
                                                               : make_float4(0.f, 0.f, 0.f, 0.f);
                else                          av = ld4(g0 + (size_t)adst * DND + (kk - DND - 2 * DED));
            } else {
                if (kk < DND) av = ld4(g0 + (size_t)arow * DND + kk);
                else {
                    float4 u = ld4(g1 + (size_t)arow * DED + (kk - DND));
                    float4 w = ld4(g2 + (size_t)arow * DED + (kk - DND));
                    av = make_float4(u.x + w.x, u.y + w.y, u.z + w.z, u.w + w.w);
                }
            }
            const int kb = lk + half * 4;
            As[kb + 0][lr] = av.x; As[kb + 1][lr] = av.y; As[kb + 2][lr] = av.z; As[kb + 3][lr] = av.w;
            float4 bv = ld4(B + (size_t)brow * K + kk);
            Bs[kb + 0][lr] = bv.x; Bs[kb + 1][lr] = bv.y; Bs[kb + 2][lr] = bv.z; Bs[kb + 3][lr] = bv.w;
        }
        __syncthreads();
#pragma unroll
        for (int kq = 0; kq < 16; ++kq) {
            float a[8], b[8];
#pragma unroll
            for (int i = 0; i < 8; i++) a[i] = As[kq][ty * 8 + i];
#pragma unroll
            for (int j = 0; j < 8; j++) b[j] = Bs[kq][tx * 8 + j];
#pragma unroll
            for (int i = 0; i < 8; i++)
#pragma unroll
                for (int j = 0; j < 8; j++)
                    acc[i][j] = fmaf(a[i], b[j], acc[i][j]);
        }
        __syncthreads();
    }
    float bsv[8], sc[8], sh[8];
#pragma unroll
    for (int j = 0; j < 8; j++) {
        int col = bn + tx * 8 + j;
        bsv[j] = bias[col];
        if (EPI == 2) { sc[j] = BN_SCALE * eg[col]; sh[j] = eb[col]; }
        else { sc[j] = 1.f; sh[j] = 0.f; }
    }
#pragma unroll
    for (int i = 0; i < 8; i++) {
        int row = bm + ty * 8 + i;
        float out[8];
#pragma unroll
        for (int j = 0; j < 8; j++) {
            float v = acc[i][j] + bsv[j];
            if (EPI == 2) v = fmaxf(fmaf(v, sc[j], sh[j]), 0.f);
            else if (EPI == 1) v = fmaxf(v, 0.f);
            out[j] = v;
        }
        float4* cp = reinterpret_cast<float4*>(C + (size_t)row * Nc + bn + tx * 8);
        cp[0] = make_float4(out[0], out[1], out[2], out[3]);
        cp[1] = make_float4(out[4], out[5], out[6], out[7]);
    }
}

// ---------------- attention: flash-style, 1 head x 32 query rows per block ----------------
__global__ __launch_bounds__(256) void attn_k(const float* __restrict__ qkv,
                                              const float* __restrict__ mask,
                                              float* __restrict__ ctx)
{
    const int h = blockIdx.y;
    const int i0 = blockIdx.x * 32;
    __shared__ float Qs[32][65];
    __shared__ float Ks[64][65];
    __shared__ float Vs[64][65];
    __shared__ float Ps[32][64];
    const int tid = threadIdx.x;
    const int qr = tid >> 3, g = tid & 7;

    for (int u = tid; u < 512; u += 256) {
        int row = u >> 4, d4 = (u & 15) * 4;
        float4 v = ld4(qkv + (size_t)(i0 + row) * (3 * DND) + h * HD + d4);
        const float scq = 0.125f;  // 1/sqrt(64)
        Qs[row][d4 + 0] = v.x * scq; Qs[row][d4 + 1] = v.y * scq;
        Qs[row][d4 + 2] = v.z * scq; Qs[row][d4 + 3] = v.w * scq;
    }
    float m = NEGF, lsum = 0.f;
    float c[8] = {};
    for (int jt = 0; jt < NN; jt += 64) {
        __syncthreads();  // protect Ks/Vs/Ps from previous iteration readers
        for (int u = tid; u < 1024; u += 256) {
            int row = u >> 4, d4 = (u & 15) * 4;
            float4 kv = ld4(qkv + (size_t)(jt + row) * (3 * DND) + DND + h * HD + d4);
            Ks[row][d4 + 0] = kv.x; Ks[row][d4 + 1] = kv.y; Ks[row][d4 + 2] = kv.z; Ks[row][d4 + 3] = kv.w;
            float4 vv = ld4(qkv + (size_t)(jt + row) * (3 * DND) + 2 * DND + h * HD + d4);
            Vs[row][d4 + 0] = vv.x; Vs[row][d4 + 1] = vv.y; Vs[row][d4 + 2] = vv.z; Vs[row][d4 + 3] = vv.w;
        }
        __syncthreads();
        float s[8];
#pragma unroll
        for (int w = 0; w < 8; w++) s[w] = 0.f;
        for (int d = 0; d < HD; d++) {
            float qv = Qs[qr][d];
#pragma unroll
            for (int w = 0; w < 8; w++) s[w] = fmaf(qv, Ks[w * 8 + g][d], s[w]);
        }
        const float* mrow = mask + (size_t)(i0 + qr) * NN + jt;
        float mloc = NEGF;
#pragma unroll
        for (int w = 0; w < 8; w++) { s[w] += mrow[w * 8 + g]; mloc = fmaxf(mloc, s[w]); }
#pragma unroll
        for (int o = 1; o < 8; o <<= 1) mloc = fmaxf(mloc, __shfl_xor(mloc, o, 8));
        float mnew = fmaxf(m, mloc);
        float alpha = __expf(m - mnew);  // m==mnew==NEGF -> expf(0)=1, state is 0 anyway
        float psum = 0.f;
#pragma unroll
        for (int w = 0; w < 8; w++) {
            float p = __expf(s[w] - mnew);
            Ps[qr][w * 8 + g] = p;
            psum += p;
        }
#pragma unroll
        for (int o = 1; o < 8; o <<= 1) psum += __shfl_xor(psum, o, 8);
        lsum = lsum * alpha + psum;
#pragma unroll
        for (int dd = 0; dd < 8; dd++) c[dd] *= alpha;
        __syncthreads();  // Ps visible to all lanes of the row (cross-wave safe)
        for (int j = 0; j < 64; j++) {
            float pj = Ps[qr][j];
#pragma unroll
            for (int dd = 0; dd < 8; dd++) c[dd] = fmaf(pj, Vs[j][g * 8 + dd], c[dd]);
        }
        m = mnew;
    }
    float inv = 1.0f / lsum;
#pragma unroll
    for (int dd = 0; dd < 8; dd++)
        ctx[(size_t)(i0 + qr) * DND + h * HD + g * 8 + dd] = c[dd] * inv;
}

// ---------------- scatter-max (te >= 0, uint-ordered atomics) ----------------
__global__ __launch_bounds__(256) void scatter_k(const float* __restrict__ te,
                                                 const int* __restrict__ srcv, const int* __restrict__ dstv,
                                                 float* __restrict__ subj, float* __restrict__ obj, int e0)
{
    int idx = blockIdx.x * 256 + threadIdx.x;
    int r = idx >> 9, cidx = idx & 511;
    int e = e0 + r;
    unsigned int v = __float_as_uint(te[idx]);
    atomicMax(reinterpret_cast<unsigned int*>(subj) + (size_t)srcv[e] * DED + cidx, v);
    atomicMax(reinterpret_cast<unsigned int*>(obj) + (size_t)dstv[e] * DED + cidx, v);
}

// ---------------- host orchestration ----------------
extern "C" void kernel_launch(void* const* d_in, const int* in_sizes, int n_in,
                              void* d_out, int out_size, void* d_ws, size_t ws_size,
                              hipStream_t stream)
{
    const float* x    = (const float*)d_in[0];
    const float* efin = (const float*)d_in[1];
    const float* pos  = (const float*)d_in[2];
    const float* inw  = (const float*)d_in[3];
    const float* inb  = (const float*)d_in[4];
    const float* ow   = (const float*)d_in[5];
    const float* ob   = (const float*)d_in[6];
    const float* etw  = (const float*)d_in[7];
    const float* etb  = (const float*)d_in[8];
    const float* etg  = (const float*)d_in[9];
    const float* etbb = (const float*)d_in[10];
    const float* unw  = (const float*)d_in[11];
    const float* unb  = (const float*)d_in[12];
    const float* uew  = (const float*)d_in[13];
    const float* ueb  = (const float*)d_in[14];
    const int*   ei   = (const int*)d_in[15];

    float* W = (float*)d_ws;
    float* mask  = W;                      // 4,194,304
    float* unionA = W + 4194304;           // table (int) / qkv
    int*   table = (int*)unionA;
    float* qkv   = unionA;                 // 3,145,728
    float* ctx   = unionA + 3145728;       // 1,048,576
    int*   rev   = (int*)(W + 8388608);    // 32,768
    float* nfA   = W + 8421376;            // 1,048,576
    float* xupd  = W + 9469952;            // 1,048,576
    float* tec   = W + 10518528;           // 2,097,152 (4096x512 chunk)
    float* subj  = W + 12615680;           // 1,048,576
    float* obj   = W + 13664256;           // 1,048,576
    float* efA   = W + 14712832;           // 16,777,216
    // total 31,490,048 floats = ~126 MB

    float* out_nf = (float*)d_out;
    float* out_ef = out_nf + (size_t)NN * DND;

    const int* srcv = ei;
    const int* dstv = ei + EE;

    // setup: edge table, reverse-edge index, attention mask
    init_table_k<<<NN * NN / 256, 256, 0, stream>>>(table);
    fill_table_k<<<EE / 256, 256, 0, stream>>>(ei, table);
    build_rev_k<<<EE / 256, 256, 0, stream>>>(ei, table, rev);
    build_mask_k<<<NN * NN / 256, 256, 0, stream>>>(table, pos, mask);

    for (int l = 0; l < 2; ++l) {
        const float* nf_cur = (l == 0) ? x : nfA;
        const float* ef_cur = (l == 0) ? efin : out_ef;
        float* ef_next = (l == 0) ? out_ef : efA;
        float* nf_next = (l == 0) ? nfA : out_nf;
        const float* inw_l  = inw  + (size_t)l * 3 * DND * DND;
        const float* inb_l  = inb  + (size_t)l * 3 * DND;
        const float* ow_l   = ow   + (size_t)l * DND * DND;
        const float* ob_l   = ob   + (size_t)l * DND;
        const float* etw_l  = etw  + (size_t)l * DED * DED;
        const float* etb_l  = etb  + (size_t)l * DED;
        const float* etg_l  = etg  + (size_t)l * DED;
        const float* etbb_l = etbb + (size_t)l * DED;
        const float* unw_l  = unw  + (size_t)l * DND * (DND + DED);
        const float* unb_l  = unb  + (size_t)l * DND;
        const float* uew_l  = uew  + (size_t)l * DED * (2 * DND + 2 * DED);
        const float* ueb_l  = ueb  + (size_t)l * DED;

        // qkv = nf @ inw^T + inb
        gemm_k<0, 0><<<dim3(NN / 128, 3 * DND / 128), 256, 0, stream>>>(
            nf_cur, inw_l, inb_l, qkv, NN, 3 * DND, DND,
            nullptr, nullptr, nullptr, nullptr, nullptr, nullptr, nullptr, nullptr);

        // masked MHSA
        attn_k<<<dim3(NN / 32, NH), 256, 0, stream>>>(qkv, mask, ctx);

        // x_upd = ctx @ ow^T + ob
        gemm_k<0, 0><<<dim3(NN / 128, DND / 128), 256, 0, stream>>>(
            ctx, ow_l, ob_l, xupd, NN, DND, DND,
            nullptr, nullptr, nullptr, nullptr, nullptr, nullptr, nullptr, nullptr);

        // scatter-max accumulators
        hipMemsetAsync(subj, 0, (size_t)NN * DED * 4, stream);
        hipMemsetAsync(obj, 0, (size_t)NN * DED * 4, stream);

        // te = relu(BN(ef @ etw^T + etb)) in chunks, fused scatter-max
        for (int c0 = 0; c0 < EE; c0 += 4096) {
            gemm_k<0, 2><<<dim3(4096 / 128, DED / 128), 256, 0, stream>>>(
                ef_cur + (size_t)c0 * DED, etw_l, etb_l, tec, 4096, DED, DED,
                nullptr, nullptr, nullptr, nullptr, nullptr, nullptr, etg_l, etbb_l);
            scatter_k<<<4096 * DED / 256, 256, 0, stream>>>(tec, srcv, dstv, subj, obj, c0);
        }

        // ef_next = (relu?)([nf[src], ef, ef[rev], nf[dst]] @ uew^T + ueb)
        if (l == 0)
            gemm_k<1, 1><<<dim3(EE / 128, DED / 128), 256, 0, stream>>>(
                nullptr, uew_l, ueb_l, ef_next, EE, DED, 2 * DND + 2 * DED,
                nf_cur, ef_cur, nullptr, srcv, dstv, rev, nullptr, nullptr);
        else
            gemm_k<1, 0><<<dim3(EE / 128, DED / 128), 256, 0, stream>>>(
                nullptr, uew_l, ueb_l, ef_next, EE, DED, 2 * DND + 2 * DED,
                nf_cur, ef_cur, nullptr, srcv, dstv, rev, nullptr, nullptr);

        // nf_next = (relu?)([x_upd, subj+obj] @ unw^T + unb)
        if (l == 0)
            gemm_k<2, 1><<<dim3(NN / 128, DND / 128), 256, 0, stream>>>(
                nullptr, unw_l, unb_l, nf_next, NN, DND, DND + DED,
                xupd, subj, obj, nullptr, nullptr, nullptr, nullptr, nullptr);
        else
            gemm_k<2, 0><<<dim3(NN / 128, DND / 128), 256, 0, stream>>>(
                nullptr, unw_l, unb_l, nf_next, NN, DND, DND + DED,
                xupd, subj, obj, nullptr, nullptr, nullptr, nullptr, nullptr);
    }

    // final ef lives in efA (layer 1 couldn't write in-place over its input) -> move to d_out
    hipMemcpyAsync(out_ef, efA, (size_t)EE * DED * 4, hipMemcpyDeviceToDevice, stream);
}

// Round 3
// 1602.012 us; speedup vs baseline: 2.7792x; 2.7792x over previous
//
#include <hip/hip_runtime.h>
#include <hip/hip_bf16.h>

#define NN 2048
#define EE 32768
#define DND 512
#define NH 8
#define HD 64
#define NEGF (-1e30f)
#define BN_SCALE 0.9999950000374997f  // 1/sqrt(1+1e-5)

typedef __attribute__((ext_vector_type(8))) short bf16x8;
typedef __attribute__((ext_vector_type(4))) float f32x4;
typedef unsigned short u16;

static __device__ __forceinline__ float4 ld4(const float* p) {
    return *reinterpret_cast<const float4*>(p);
}
static __device__ __forceinline__ u16 f2b(float f) {
    __hip_bfloat16 h = __float2bfloat16(f);
    return *reinterpret_cast<u16*>(&h);
}
static __device__ __forceinline__ void gl_lds(const u16* g, u16* l) {
    __builtin_amdgcn_global_load_lds((const __attribute__((address_space(1))) void*)g,
                                     (__attribute__((address_space(3))) void*)l, 16, 0, 0);
}

// ---------------- setup kernels ----------------

__global__ __launch_bounds__(256) void init_table_k(int* __restrict__ t) {
    int i = blockIdx.x * 256 + threadIdx.x;
    t[i] = -1;
}

__global__ __launch_bounds__(256) void fill_table_k(const int* __restrict__ ei, int* __restrict__ t) {
    int e = blockIdx.x * 256 + threadIdx.x;
    if (e < EE) t[(size_t)ei[e] * NN + ei[EE + e]] = e;
}

__global__ __launch_bounds__(256) void build_rev_k(const int* __restrict__ ei, const int* __restrict__ t,
                                                   int* __restrict__ rev) {
    int e = blockIdx.x * 256 + threadIdx.x;
    if (e < EE) rev[e] = t[(size_t)ei[EE + e] * NN + ei[e]];
}

__global__ __launch_bounds__(256) void build_mask_k(const int* __restrict__ t, const float* __restrict__ pos,
                                                    float* __restrict__ mask) {
    int idx = blockIdx.x * 256 + threadIdx.x;
    int i = idx >> 11, j = idx & (NN - 1);
    float v;
    if (i == j) {
        v = 1.0f;
    } else if (t[idx] >= 0 || t[(size_t)j * NN + i] >= 0) {
        float dx = pos[i * 3 + 0] - pos[j * 3 + 0];
        float dy = pos[i * 3 + 1] - pos[j * 3 + 1];
        float dz = pos[i * 3 + 2] - pos[j * 3 + 2];
        v = 1.0f / (sqrtf(dx * dx + dy * dy + dz * dz) + 1e-6f);
    } else {
        v = NEGF;
    }
    mask[idx] = v;
}

// ---------------- f32 -> bf16 conversion (8 elems/thread) ----------------
__global__ __launch_bounds__(256) void conv_k(const float* __restrict__ src, u16* __restrict__ dst) {
    int i = (blockIdx.x * 256 + threadIdx.x) * 8;
    float4 a = ld4(src + i), b = ld4(src + i + 4);
    u16 o[8];
    o[0] = f2b(a.x); o[1] = f2b(a.y); o[2] = f2b(a.z); o[3] = f2b(a.w);
    o[4] = f2b(b.x); o[5] = f2b(b.y); o[6] = f2b(b.z); o[7] = f2b(b.w);
    *reinterpret_cast<int4*>(dst + i) = *reinterpret_cast<const int4*>(o);
}

// sumso = bf16(subj + obj)
__global__ __launch_bounds__(256) void sumso_k(const float* __restrict__ s, const float* __restrict__ o,
                                               u16* __restrict__ dst) {
    int i = (blockIdx.x * 256 + threadIdx.x) * 8;
    float4 a = ld4(s + i), b = ld4(o + i), c = ld4(s + i + 4), d = ld4(o + i + 4);
    u16 ov[8];
    ov[0] = f2b(a.x + b.x); ov[1] = f2b(a.y + b.y); ov[2] = f2b(a.z + b.z); ov[3] = f2b(a.w + b.w);
    ov[4] = f2b(c.x + d.x); ov[5] = f2b(c.y + d.y); ov[6] = f2b(c.z + d.z); ov[7] = f2b(c.w + d.w);
    *reinterpret_cast<int4*>(dst + i) = *reinterpret_cast<const int4*>(ov);
}

// ---------------- MFMA GEMM: C[M,Nc] = epi(Agather[M,K](bf16) @ B[Nc,K](bf16)^T + bias) ----
// MODE 0: A plain row-major bf16 M x K
// MODE 1: A = [g0[src], g1, g1[rev]|zero, g0[dst]]   (K = 2048)
// MODE 2: A = [g0, g1]                               (K = 1024)
// EPI 0: +bias   EPI 1: relu(+bias)   EPI 2: relu((+bias)*BN_SCALE*eg+eb) + atomicMax scatter (no C write)
// LDS layout: [kq 0..3][row 0..127][8 bf16]  -> conflict-free ds_read_b128 fragments
template <int MODE, int EPI, int WF32, int WBF16>
__global__ __launch_bounds__(256) void mgemm_k(
    const u16* __restrict__ A, const u16* __restrict__ B, const float* __restrict__ bias,
    float* __restrict__ Cf, u16* __restrict__ Cb, int M, int Nc, int K,
    const u16* __restrict__ g0, const u16* __restrict__ g1, const u16* __restrict__ gz,
    const int* __restrict__ srcv, const int* __restrict__ dstv, const int* __restrict__ revv,
    const float* __restrict__ eg, const float* __restrict__ eb,
    float* __restrict__ subj, float* __restrict__ obj)
{
    __shared__ u16 As2[4096];
    __shared__ u16 Bs2[4096];
    const int tid = threadIdx.x, lane = tid & 63, w = tid >> 6;
    const int wr = w >> 1, wc = w & 1;
    const int bm = blockIdx.x * 128, bn = blockIdx.y * 128;

    // hoisted per-lane row pointers (each lane loads rows lane and 64+lane of the tile)
    const u16* pa0[2];
    const u16* pa1[2];
    const u16* pa2[2];
    const u16* pa3[2];
    const u16* pb[2];
#pragma unroll
    for (int h = 0; h < 2; ++h) {
        const int r = bm + h * 64 + lane;
        if (MODE == 0) {
            pa0[h] = A + (size_t)r * K + w * 8;
        } else if (MODE == 1) {
            pa0[h] = g0 + (size_t)srcv[r] * DND + w * 8;
            pa1[h] = g1 + (size_t)r * DND + w * 8;
            const int rv = revv[r];
            pa2[h] = (rv >= 0) ? (g1 + (size_t)rv * DND + w * 8) : (gz + w * 8);
            pa3[h] = g0 + (size_t)dstv[r] * DND + w * 8;
        } else {
            pa0[h] = g0 + (size_t)r * DND + w * 8;
            pa1[h] = g1 + (size_t)r * DND + w * 8;
        }
        pb[h] = B + (size_t)(bn + h * 64 + lane) * K + w * 8;
    }

    f32x4 acc[4][4] = {};
    const int nks = K >> 5;
    const int kq = lane >> 4, li = lane & 15;
    for (int ks = 0; ks < nks; ++ks) {
        const int k0 = ks * 32;
        const u16* ga[2];
        if (MODE == 0) {
            ga[0] = pa0[0] + k0; ga[1] = pa0[1] + k0;
        } else if (MODE == 1) {
            const int seg = k0 >> 9, koff = k0 & 511;
#pragma unroll
            for (int h = 0; h < 2; ++h)
                ga[h] = (seg == 0 ? pa0[h] : seg == 1 ? pa1[h] : seg == 2 ? pa2[h] : pa3[h]) + koff;
        } else {
            const int seg = k0 >> 9, koff = k0 & 511;
#pragma unroll
            for (int h = 0; h < 2; ++h)
                ga[h] = (seg == 0 ? pa0[h] : pa1[h]) + koff;
        }
        __syncthreads();
        gl_lds(ga[0], As2 + w * 1024);
        gl_lds(ga[1], As2 + w * 1024 + 512);
        gl_lds(pb[0] + k0, Bs2 + w * 1024);
        gl_lds(pb[1] + k0, Bs2 + w * 1024 + 512);
        __syncthreads();
        bf16x8 af[4], bf[4];
#pragma unroll
        for (int m = 0; m < 4; ++m)
            af[m] = *reinterpret_cast<const bf16x8*>(&As2[kq * 1024 + (wr * 64 + m * 16 + li) * 8]);
#pragma unroll
        for (int n = 0; n < 4; ++n)
            bf[n] = *reinterpret_cast<const bf16x8*>(&Bs2[kq * 1024 + (wc * 64 + n * 16 + li) * 8]);
#pragma unroll
        for (int m = 0; m < 4; ++m)
#pragma unroll
            for (int n = 0; n < 4; ++n)
                acc[m][n] = __builtin_amdgcn_mfma_f32_16x16x32_bf16(af[m], bf[n], acc[m][n], 0, 0, 0);
    }

    // epilogue: C[row=(lane>>4)*4+i][col=lane&15] per 16x16 fragment
    float bsv[4], scv[4], shv[4];
#pragma unroll
    for (int n = 0; n < 4; ++n) {
        const int col = bn + wc * 64 + n * 16 + li;
        bsv[n] = bias[col];
        if (EPI == 2) { scv[n] = BN_SCALE * eg[col]; shv[n] = eb[col]; }
    }
#pragma unroll
    for (int m = 0; m < 4; ++m) {
        int se[4], de[4];
        if (EPI == 2) {
#pragma unroll
            for (int i = 0; i < 4; ++i) {
                const int r = bm + wr * 64 + m * 16 + (lane >> 4) * 4 + i;
                se[i] = srcv[r]; de[i] = dstv[r];
            }
        }
#pragma unroll
        for (int n = 0; n < 4; ++n) {
            const int col = bn + wc * 64 + n * 16 + li;
#pragma unroll
            for (int i = 0; i < 4; ++i) {
                float v = acc[m][n][i] + bsv[n];
                if (EPI == 2) {
                    v = fmaxf(fmaf(v, scv[n], shv[n]), 0.f);
                    const unsigned uv = __float_as_uint(v);
                    atomicMax(reinterpret_cast<unsigned*>(subj) + (size_t)se[i] * DND + col, uv);
                    atomicMax(reinterpret_cast<unsigned*>(obj) + (size_t)de[i] * DND + col, uv);
                } else {
                    if (EPI == 1) v = fmaxf(v, 0.f);
                    const int r = bm + wr * 64 + m * 16 + (lane >> 4) * 4 + i;
                    if (WF32) Cf[(size_t)r * Nc + col] = v;
                    if (WBF16) Cb[(size_t)r * Nc + col] = f2b(v);
                }
            }
        }
    }
}

// ---------------- attention: flash-style, 1 head x 32 query rows per block ----------------
__global__ __launch_bounds__(256) void attn_k(const float* __restrict__ qkv,
                                              const float* __restrict__ mask,
                                              u16* __restrict__ ctxb)
{
    const int h = blockIdx.y;
    const int i0 = blockIdx.x * 32;
    __shared__ float Qs[32][65];
    __shared__ float Ks[64][65];
    __shared__ float Vs[64][65];
    __shared__ float Ps[32][64];
    const int tid = threadIdx.x;
    const int qr = tid >> 3, g = tid & 7;

    for (int u = tid; u < 512; u += 256) {
        int row = u >> 4, d4 = (u & 15) * 4;
        float4 v = ld4(qkv + (size_t)(i0 + row) * (3 * DND) + h * HD + d4);
        const float scq = 0.125f;  // 1/sqrt(64)
        Qs[row][d4 + 0] = v.x * scq; Qs[row][d4 + 1] = v.y * scq;
        Qs[row][d4 + 2] = v.z * scq; Qs[row][d4 + 3] = v.w * scq;
    }
    float m = NEGF, lsum = 0.f;
    float c[8] = {};
    for (int jt = 0; jt < NN; jt += 64) {
        __syncthreads();
        for (int u = tid; u < 1024; u += 256) {
            int row = u >> 4, d4 = (u & 15) * 4;
            float4 kv = ld4(qkv + (size_t)(jt + row) * (3 * DND) + DND + h * HD + d4);
            Ks[row][d4 + 0] = kv.x; Ks[row][d4 + 1] = kv.y; Ks[row][d4 + 2] = kv.z; Ks[row][d4 + 3] = kv.w;
            float4 vv = ld4(qkv + (size_t)(jt + row) * (3 * DND) + 2 * DND + h * HD + d4);
            Vs[row][d4 + 0] = vv.x; Vs[row][d4 + 1] = vv.y; Vs[row][d4 + 2] = vv.z; Vs[row][d4 + 3] = vv.w;
        }
        __syncthreads();
        float s[8];
#pragma unroll
        for (int w = 0; w < 8; w++) s[w] = 0.f;
        for (int d = 0; d < HD; d++) {
            float qv = Qs[qr][d];
#pragma unroll
            for (int w = 0; w < 8; w++) s[w] = fmaf(qv, Ks[w * 8 + g][d], s[w]);
        }
        const float* mrow = mask + (size_t)(i0 + qr) * NN + jt;
        float mloc = NEGF;
#pragma unroll
        for (int w = 0; w < 8; w++) { s[w] += mrow[w * 8 + g]; mloc = fmaxf(mloc, s[w]); }
#pragma unroll
        for (int o = 1; o < 8; o <<= 1) mloc = fmaxf(mloc, __shfl_xor(mloc, o, 8));
        float mnew = fmaxf(m, mloc);
        float alpha = __expf(m - mnew);
        float psum = 0.f;
#pragma unroll
        for (int w = 0; w < 8; w++) {
            float p = __expf(s[w] - mnew);
            Ps[qr][w * 8 + g] = p;
            psum += p;
        }
#pragma unroll
        for (int o = 1; o < 8; o <<= 1) psum += __shfl_xor(psum, o, 8);
        lsum = lsum * alpha + psum;
#pragma unroll
        for (int dd = 0; dd < 8; dd++) c[dd] *= alpha;
        __syncthreads();
        for (int j = 0; j < 64; j++) {
            float pj = Ps[qr][j];
#pragma unroll
            for (int dd = 0; dd < 8; dd++) c[dd] = fmaf(pj, Vs[j][g * 8 + dd], c[dd]);
        }
        m = mnew;
    }
    float inv = 1.0f / lsum;
#pragma unroll
    for (int dd = 0; dd < 8; dd++)
        ctxb[(size_t)(i0 + qr) * DND + h * HD + g * 8 + dd] = f2b(c[dd] * inv);
}

// ---------------- host orchestration ----------------
extern "C" void kernel_launch(void* const* d_in, const int* in_sizes, int n_in,
                              void* d_out, int out_size, void* d_ws, size_t ws_size,
                              hipStream_t stream)
{
    const float* x    = (const float*)d_in[0];
    const float* efin = (const float*)d_in[1];
    const float* pos  = (const float*)d_in[2];
    const float* inw  = (const float*)d_in[3];
    const float* inb  = (const float*)d_in[4];
    const float* ow   = (const float*)d_in[5];
    const float* ob   = (const float*)d_in[6];
    const float* etw  = (const float*)d_in[7];
    const float* etb  = (const float*)d_in[8];
    const float* etg  = (const float*)d_in[9];
    const float* etbb = (const float*)d_in[10];
    const float* unw  = (const float*)d_in[11];
    const float* unb  = (const float*)d_in[12];
    const float* uew  = (const float*)d_in[13];
    const float* ueb  = (const float*)d_in[14];
    const int*   ei   = (const int*)d_in[15];

    // workspace layout (offsets in floats)
    float* W = (float*)d_ws;
    float* mask  = W;                                //         0 .. 4,194,304   (NN*NN)
    float* qkv   = W + 4194304;                      // 4,194,304 .. 7,340,032   (NN*3*DND)
    float* subj  = W + 7340032;                      // 7,340,032 .. 8,388,608   (NN*DND)
    float* obj   = W + 8388608;                      // 8,388,608 .. 9,437,184   (NN*DND)
    int*   rev   = (int*)(W + 9437184);              // 9,437,184 .. 9,469,952   (EE ints)
    u16*   zero  = (u16*)(W + 9469952);              // 9,469,952 .. 9,470,464   (1024 u16)
    u16*   ctxb  = (u16*)(W + 9470464);              // .. 9,994,752    (NN*DND u16)
    u16*   xupdb = (u16*)(W + 9994752);              // .. 10,519,040   (NN*DND u16)
    u16*   sums  = (u16*)(W + 10519040);             // .. 11,043,328   (NN*DND u16)
    u16*   nfb   = (u16*)(W + 11043328);             // .. 11,567,616   (NN*DND u16)
    u16*   wbf   = (u16*)(W + 11567616);             // .. 14,451,200   (5,767,168 u16)
    u16*   efbA  = (u16*)(W + 14451200);             // .. 22,839,808   (EE*DND u16)
    u16*   efbB  = (u16*)(W + 22839808);             // .. 31,228,416   (EE*DND u16)
    int*   table = (int*)efbA;                       // alias: setup-only (needs 16 MB < 32 MB)
    // total: 31,228,416 floats = 124.9 MB

    u16* inwb = wbf;
    u16* owb  = wbf + 1572864;
    u16* etwb = wbf + 2097152;
    u16* unwb = wbf + 2621440;
    u16* uewb = wbf + 3670016;

    float* out_nf = (float*)d_out;
    float* out_ef = out_nf + (size_t)NN * DND;

    const int* srcv = ei;
    const int* dstv = ei + EE;

    // setup: edge table, reverse-edge index, attention mask (table aliases efbA; done before conv)
    init_table_k<<<NN * NN / 256, 256, 0, stream>>>(table);
    fill_table_k<<<EE / 256, 256, 0, stream>>>(ei, table);
    build_rev_k<<<EE / 256, 256, 0, stream>>>(ei, table, rev);
    build_mask_k<<<NN * NN / 256, 256, 0, stream>>>(table, pos, mask);
    hipMemsetAsync(zero, 0, 2048, stream);

    // bf16 weight copies (both layers at once)
    conv_k<<<1572864 / 2048, 256, 0, stream>>>(inw, inwb);
    conv_k<<<524288 / 2048, 256, 0, stream>>>(ow, owb);
    conv_k<<<524288 / 2048, 256, 0, stream>>>(etw, etwb);
    conv_k<<<1048576 / 2048, 256, 0, stream>>>(unw, unwb);
    conv_k<<<2097152 / 2048, 256, 0, stream>>>(uew, uewb);
    // bf16 activations for layer 0
    conv_k<<<1048576 / 2048, 256, 0, stream>>>(x, nfb);
    conv_k<<<16777216 / 2048, 256, 0, stream>>>(efin, efbA);

    for (int l = 0; l < 2; ++l) {
        const u16* efb_cur = l ? efbB : efbA;
        const u16* inwb_l = inwb + (size_t)l * 786432;
        const u16* owb_l  = owb  + (size_t)l * 262144;
        const u16* etwb_l = etwb + (size_t)l * 262144;
        const u16* unwb_l = unwb + (size_t)l * 524288;
        const u16* uewb_l = uewb + (size_t)l * 1048576;
        const float* inb_l  = inb  + (size_t)l * 1536;
        const float* ob_l   = ob   + (size_t)l * 512;
        const float* etb_l  = etb  + (size_t)l * 512;
        const float* etg_l  = etg  + (size_t)l * 512;
        const float* etbb_l = etbb + (size_t)l * 512;
        const float* unb_l  = unb  + (size_t)l * 512;
        const float* ueb_l  = ueb  + (size_t)l * 512;

        // qkv = nf @ inw^T + inb   (f32 out for attention)
        mgemm_k<0, 0, 1, 0><<<dim3(16, 12), 256, 0, stream>>>(
            nfb, inwb_l, inb_l, qkv, nullptr, NN, 3 * DND, DND,
            nullptr, nullptr, nullptr, nullptr, nullptr, nullptr, nullptr, nullptr, nullptr, nullptr);

        // masked MHSA -> ctx (bf16)
        attn_k<<<dim3(NN / 32, NH), 256, 0, stream>>>(qkv, mask, ctxb);

        // x_upd = ctx @ ow^T + ob  (bf16 out, only consumed by update_node gather)
        mgemm_k<0, 0, 0, 1><<<dim3(16, 4), 256, 0, stream>>>(
            ctxb, owb_l, ob_l, nullptr, xupdb, NN, DND, DND,
            nullptr, nullptr, nullptr, nullptr, nullptr, nullptr, nullptr, nullptr, nullptr, nullptr);

        // scatter-max accumulators
        hipMemsetAsync(subj, 0, (size_t)NN * DND * 4, stream);
        hipMemsetAsync(obj, 0, (size_t)NN * DND * 4, stream);

        // te = relu(BN(ef @ etw^T + etb)) with fused atomicMax scatter (no C write)
        mgemm_k<0, 2, 0, 0><<<dim3(256, 4), 256, 0, stream>>>(
            efb_cur, etwb_l, etb_l, nullptr, nullptr, EE, DND, DND,
            nullptr, nullptr, nullptr, srcv, dstv, nullptr, etg_l, etbb_l, subj, obj);

        // sumso = bf16(subj + obj)
        sumso_k<<<1048576 / 2048, 256, 0, stream>>>(subj, obj, sums);

        // ef_next = (relu?)([nf[src], ef, ef[rev], nf[dst]] @ uew^T + ueb)
        if (l == 0)
            mgemm_k<1, 1, 0, 1><<<dim3(256, 4), 256, 0, stream>>>(
                nullptr, uewb_l, ueb_l, nullptr, efbB, EE, DND, 2048,
                nfb, efb_cur, zero, srcv, dstv, rev, nullptr, nullptr, nullptr, nullptr);
        else
            mgemm_k<1, 0, 1, 0><<<dim3(256, 4), 256, 0, stream>>>(
                nullptr, uewb_l, ueb_l, out_ef, nullptr, EE, DND, 2048,
                nfb, efb_cur, zero, srcv, dstv, rev, nullptr, nullptr, nullptr, nullptr);

        // nf_next = (relu?)([x_upd, subj+obj] @ unw^T + unb)
        if (l == 0)
            mgemm_k<2, 1, 0, 1><<<dim3(16, 4), 256, 0, stream>>>(
                nullptr, unwb_l, unb_l, nullptr, nfb, NN, DND, 1024,
                xupdb, sums, nullptr, nullptr, nullptr, nullptr, nullptr, nullptr, nullptr, nullptr);
        else
            mgemm_k<2, 0, 1, 0><<<dim3(16, 4), 256, 0, stream>>>(
                nullptr, unwb_l, unb_l, out_nf, nullptr, NN, DND, 1024,
                xupdb, sums, nullptr, nullptr, nullptr, nullptr, nullptr, nullptr, nullptr, nullptr);
    }
}

// Round 4
// 839.213 us; speedup vs baseline: 5.3054x; 1.9089x over previous
//
#include <hip/hip_runtime.h>
#include <hip/hip_bf16.h>

#define NN 2048
#define EE 32768
#define DND 512
#define NH 8
#define HD 64
#define MAXD 128
#define NEGF (-1e30f)
#define BN_SCALE 0.9999950000374997f  // 1/sqrt(1+1e-5)

typedef __attribute__((ext_vector_type(8))) short bf16x8;
typedef __attribute__((ext_vector_type(4))) float f32x4;
typedef unsigned short u16;

static __device__ __forceinline__ float4 ld4(const float* p) {
    return *reinterpret_cast<const float4*>(p);
}
static __device__ __forceinline__ u16 f2b(float f) {
    __hip_bfloat16 h = __float2bfloat16(f);
    return *reinterpret_cast<u16*>(&h);
}
static __device__ __forceinline__ void gl_lds(const u16* g, u16* l) {
    __builtin_amdgcn_global_load_lds((const __attribute__((address_space(1))) void*)g,
                                     (__attribute__((address_space(3))) void*)l, 16, 0, 0);
}

// ---------------- setup kernels ----------------

__global__ __launch_bounds__(256) void init_table_k(int* __restrict__ t) {
    int i = blockIdx.x * 256 + threadIdx.x;
    t[i] = -1;
}

__global__ __launch_bounds__(256) void fill_table_k(const int* __restrict__ ei, int* __restrict__ t) {
    int e = blockIdx.x * 256 + threadIdx.x;
    if (e < EE) t[(size_t)ei[e] * NN + ei[EE + e]] = e;
}

__global__ __launch_bounds__(256) void build_rev_k(const int* __restrict__ ei, const int* __restrict__ t,
                                                   int* __restrict__ rev) {
    int e = blockIdx.x * 256 + threadIdx.x;
    if (e < EE) rev[e] = t[(size_t)ei[EE + e] * NN + ei[e]];
}

// CSR: slot 0 = self (weight 1.0), then neighbors
__global__ __launch_bounds__(256) void init_csr_k(int* __restrict__ adj, float* __restrict__ wadj,
                                                  int* __restrict__ cnt) {
    int i = blockIdx.x * 256 + threadIdx.x;
    if (i < NN) { cnt[i] = 1; adj[i * MAXD] = i; wadj[i * MAXD] = 1.0f; }
}

__global__ __launch_bounds__(256) void fill_csr_k(const int* __restrict__ ei, const int* __restrict__ rev,
                                                  const float* __restrict__ pos,
                                                  int* __restrict__ adj, float* __restrict__ wadj,
                                                  int* __restrict__ cnt) {
    int e = blockIdx.x * 256 + threadIdx.x;
    if (e >= EE) return;
    int s = ei[e], d = ei[EE + e];
    float dx = pos[s * 3 + 0] - pos[d * 3 + 0];
    float dy = pos[s * 3 + 1] - pos[d * 3 + 1];
    float dz = pos[s * 3 + 2] - pos[d * 3 + 2];
    float w = 1.0f / (sqrtf(dx * dx + dy * dy + dz * dz) + 1e-6f);
    int slot = atomicAdd(&cnt[s], 1);
    if (slot < MAXD) { adj[s * MAXD + slot] = d; wadj[s * MAXD + slot] = w; }
    if (rev[e] < 0) {  // symmetric pair not otherwise present -> add mirror
        slot = atomicAdd(&cnt[d], 1);
        if (slot < MAXD) { adj[d * MAXD + slot] = s; wadj[d * MAXD + slot] = w; }
    }
}

// ---------------- f32 -> bf16 conversion (8 elems/thread) ----------------
__global__ __launch_bounds__(256) void conv_k(const float* __restrict__ src, u16* __restrict__ dst) {
    int i = (blockIdx.x * 256 + threadIdx.x) * 8;
    float4 a = ld4(src + i), b = ld4(src + i + 4);
    u16 o[8];
    o[0] = f2b(a.x); o[1] = f2b(a.y); o[2] = f2b(a.z); o[3] = f2b(a.w);
    o[4] = f2b(b.x); o[5] = f2b(b.y); o[6] = f2b(b.z); o[7] = f2b(b.w);
    *reinterpret_cast<int4*>(dst + i) = *reinterpret_cast<const int4*>(o);
}

// sumso = bf16(subj + obj)
__global__ __launch_bounds__(256) void sumso_k(const float* __restrict__ s, const float* __restrict__ o,
                                               u16* __restrict__ dst) {
    int i = (blockIdx.x * 256 + threadIdx.x) * 8;
    float4 a = ld4(s + i), b = ld4(o + i), c = ld4(s + i + 4), d = ld4(o + i + 4);
    u16 ov[8];
    ov[0] = f2b(a.x + b.x); ov[1] = f2b(a.y + b.y); ov[2] = f2b(a.z + b.z); ov[3] = f2b(a.w + b.w);
    ov[4] = f2b(c.x + d.x); ov[5] = f2b(c.y + d.y); ov[6] = f2b(c.z + d.z); ov[7] = f2b(c.w + d.w);
    *reinterpret_cast<int4*>(dst + i) = *reinterpret_cast<const int4*>(ov);
}

// ---------------- MFMA GEMM: C[M,Nc] = epi(Agather[M,K](bf16) @ B[Nc,K](bf16)^T + bias) ----
// MODE 0: A plain row-major bf16 M x K
// MODE 1: A = [g0[src], g1, g1[rev]|zero, g0[dst]]   (K = 2048)
// MODE 2: A = [g0, g1]                               (K = 1024)
// EPI 0: +bias   EPI 1: relu(+bias)   EPI 2: relu((+bias)*BN_SCALE*eg+eb) + atomicMax scatter (no C write)
// LDS layout: [kq 0..3][row 0..127][8 bf16]  -> conflict-free ds_read_b128 fragments
template <int MODE, int EPI, int WF32, int WBF16>
__global__ __launch_bounds__(256) void mgemm_k(
    const u16* __restrict__ A, const u16* __restrict__ B, const float* __restrict__ bias,
    float* __restrict__ Cf, u16* __restrict__ Cb, int M, int Nc, int K,
    const u16* __restrict__ g0, const u16* __restrict__ g1, const u16* __restrict__ gz,
    const int* __restrict__ srcv, const int* __restrict__ dstv, const int* __restrict__ revv,
    const float* __restrict__ eg, const float* __restrict__ eb,
    float* __restrict__ subj, float* __restrict__ obj)
{
    __shared__ u16 As2[4096];
    __shared__ u16 Bs2[4096];
    const int tid = threadIdx.x, lane = tid & 63, w = tid >> 6;
    const int wr = w >> 1, wc = w & 1;
    const int bm = blockIdx.x * 128, bn = blockIdx.y * 128;

    const u16* pa0[2];
    const u16* pa1[2];
    const u16* pa2[2];
    const u16* pa3[2];
    const u16* pb[2];
#pragma unroll
    for (int h = 0; h < 2; ++h) {
        const int r = bm + h * 64 + lane;
        if (MODE == 0) {
            pa0[h] = A + (size_t)r * K + w * 8;
        } else if (MODE == 1) {
            pa0[h] = g0 + (size_t)srcv[r] * DND + w * 8;
            pa1[h] = g1 + (size_t)r * DND + w * 8;
            const int rv = revv[r];
            pa2[h] = (rv >= 0) ? (g1 + (size_t)rv * DND + w * 8) : (gz + w * 8);
            pa3[h] = g0 + (size_t)dstv[r] * DND + w * 8;
        } else {
            pa0[h] = g0 + (size_t)r * DND + w * 8;
            pa1[h] = g1 + (size_t)r * DND + w * 8;
        }
        pb[h] = B + (size_t)(bn + h * 64 + lane) * K + w * 8;
    }

    f32x4 acc[4][4] = {};
    const int nks = K >> 5;
    const int kq = lane >> 4, li = lane & 15;
    for (int ks = 0; ks < nks; ++ks) {
        const int k0 = ks * 32;
        const u16* ga[2];
        if (MODE == 0) {
            ga[0] = pa0[0] + k0; ga[1] = pa0[1] + k0;
        } else if (MODE == 1) {
            const int seg = k0 >> 9, koff = k0 & 511;
#pragma unroll
            for (int h = 0; h < 2; ++h)
                ga[h] = (seg == 0 ? pa0[h] : seg == 1 ? pa1[h] : seg == 2 ? pa2[h] : pa3[h]) + koff;
        } else {
            const int seg = k0 >> 9, koff = k0 & 511;
#pragma unroll
            for (int h = 0; h < 2; ++h)
                ga[h] = (seg == 0 ? pa0[h] : pa1[h]) + koff;
        }
        __syncthreads();
        gl_lds(ga[0], As2 + w * 1024);
        gl_lds(ga[1], As2 + w * 1024 + 512);
        gl_lds(pb[0] + k0, Bs2 + w * 1024);
        gl_lds(pb[1] + k0, Bs2 + w * 1024 + 512);
        __syncthreads();
        bf16x8 af[4], bf[4];
#pragma unroll
        for (int m = 0; m < 4; ++m)
            af[m] = *reinterpret_cast<const bf16x8*>(&As2[kq * 1024 + (wr * 64 + m * 16 + li) * 8]);
#pragma unroll
        for (int n = 0; n < 4; ++n)
            bf[n] = *reinterpret_cast<const bf16x8*>(&Bs2[kq * 1024 + (wc * 64 + n * 16 + li) * 8]);
#pragma unroll
        for (int m = 0; m < 4; ++m)
#pragma unroll
            for (int n = 0; n < 4; ++n)
                acc[m][n] = __builtin_amdgcn_mfma_f32_16x16x32_bf16(af[m], bf[n], acc[m][n], 0, 0, 0);
    }

    float bsv[4], scv[4], shv[4];
#pragma unroll
    for (int n = 0; n < 4; ++n) {
        const int col = bn + wc * 64 + n * 16 + li;
        bsv[n] = bias[col];
        if (EPI == 2) { scv[n] = BN_SCALE * eg[col]; shv[n] = eb[col]; }
    }
#pragma unroll
    for (int m = 0; m < 4; ++m) {
        int se[4], de[4];
        if (EPI == 2) {
#pragma unroll
            for (int i = 0; i < 4; ++i) {
                const int r = bm + wr * 64 + m * 16 + (lane >> 4) * 4 + i;
                se[i] = srcv[r]; de[i] = dstv[r];
            }
        }
#pragma unroll
        for (int n = 0; n < 4; ++n) {
            const int col = bn + wc * 64 + n * 16 + li;
#pragma unroll
            for (int i = 0; i < 4; ++i) {
                float v = acc[m][n][i] + bsv[n];
                if (EPI == 2) {
                    v = fmaxf(fmaf(v, scv[n], shv[n]), 0.f);
                    const unsigned uv = __float_as_uint(v);
                    atomicMax(reinterpret_cast<unsigned*>(subj) + (size_t)se[i] * DND + col, uv);
                    atomicMax(reinterpret_cast<unsigned*>(obj) + (size_t)de[i] * DND + col, uv);
                } else {
                    if (EPI == 1) v = fmaxf(v, 0.f);
                    const int r = bm + wr * 64 + m * 16 + (lane >> 4) * 4 + i;
                    if (WF32) Cf[(size_t)r * Nc + col] = v;
                    if (WBF16) Cb[(size_t)r * Nc + col] = f2b(v);
                }
            }
        }
    }
}

// ---------------- sparse attention: 1 wave per (node, head) ----------------
// Dense softmax with -inf mask == sparse softmax over CSR neighbor list.
// Phase 1: lane = neighbor slot (s = q.k_j + w_ij), 64-lane shuffle online softmax.
// Phase 2: lane = output dim, p/j broadcast via shfl, coalesced V-row reads.
__global__ __launch_bounds__(256) void attn_sp_k(const float* __restrict__ qkv,
                                                 const int* __restrict__ adj,
                                                 const float* __restrict__ wadj,
                                                 const int* __restrict__ cnt,
                                                 u16* __restrict__ ctxb)
{
    const int i = blockIdx.x;
    const int wv = threadIdx.x >> 6, lane = threadIdx.x & 63;
    const int h = blockIdx.y * 4 + wv;
    __shared__ float qs[4][64];
    qs[wv][lane] = qkv[(size_t)i * 1536 + h * HD + lane] * 0.125f;  // 1/sqrt(64)
    __syncthreads();
    int deg = cnt[i];
    if (deg > MAXD) deg = MAXD;
    float m = -3.0e38f, lsum = 0.f, c = 0.f;
    for (int base = 0; base < deg; base += 64) {
        int nn_ = deg - base; if (nn_ > 64) nn_ = 64;
        int j = 0;
        float s = NEGF;
        if (lane < nn_) {
            j = adj[i * MAXD + base + lane];
            const float wgt = wadj[i * MAXD + base + lane];
            const float* kr = qkv + (size_t)j * 1536 + DND + h * HD;
            float accd = 0.f;
#pragma unroll
            for (int d4 = 0; d4 < 16; ++d4) {
                float4 kv = ld4(kr + d4 * 4);
                accd = fmaf(qs[wv][d4 * 4 + 0], kv.x, accd);
                accd = fmaf(qs[wv][d4 * 4 + 1], kv.y, accd);
                accd = fmaf(qs[wv][d4 * 4 + 2], kv.z, accd);
                accd = fmaf(qs[wv][d4 * 4 + 3], kv.w, accd);
            }
            s = accd + wgt;
        }
        float mloc = s;
#pragma unroll
        for (int o = 1; o < 64; o <<= 1) mloc = fmaxf(mloc, __shfl_xor(mloc, o, 64));
        const float mnew = fmaxf(m, mloc);
        const float alpha = __expf(m - mnew);
        const float p = (lane < nn_) ? __expf(s - mnew) : 0.f;
        float ps = p;
#pragma unroll
        for (int o = 1; o < 64; o <<= 1) ps += __shfl_xor(ps, o, 64);
        lsum = lsum * alpha + ps;
        c *= alpha;
        for (int l = 0; l < nn_; ++l) {
            const float pj = __shfl(p, l, 64);
            const int jj = __shfl(j, l, 64);
            c = fmaf(pj, qkv[(size_t)jj * 1536 + 2 * DND + h * HD + lane], c);
        }
        m = mnew;
    }
    ctxb[(size_t)i * DND + h * HD + lane] = f2b(c / lsum);
}

// ---------------- host orchestration ----------------
extern "C" void kernel_launch(void* const* d_in, const int* in_sizes, int n_in,
                              void* d_out, int out_size, void* d_ws, size_t ws_size,
                              hipStream_t stream)
{
    const float* x    = (const float*)d_in[0];
    const float* efin = (const float*)d_in[1];
    const float* pos  = (const float*)d_in[2];
    const float* inw  = (const float*)d_in[3];
    const float* inb  = (const float*)d_in[4];
    const float* ow   = (const float*)d_in[5];
    const float* ob   = (const float*)d_in[6];
    const float* etw  = (const float*)d_in[7];
    const float* etb  = (const float*)d_in[8];
    const float* etg  = (const float*)d_in[9];
    const float* etbb = (const float*)d_in[10];
    const float* unw  = (const float*)d_in[11];
    const float* unb  = (const float*)d_in[12];
    const float* uew  = (const float*)d_in[13];
    const float* ueb  = (const float*)d_in[14];
    const int*   ei   = (const int*)d_in[15];

    // workspace layout (offsets in floats)
    float* W = (float*)d_ws;
    float* qkv   = W;                                //          0 .. 3,145,728  (NN*3*DND)
    float* subj  = W + 3145728;                      //  3,145,728 .. 4,194,304  (NN*DND)
    float* obj   = W + 4194304;                      //  4,194,304 .. 5,242,880  (NN*DND)
    int*   rev   = (int*)(W + 5242880);              //  .. 5,275,648  (EE ints)
    u16*   zero  = (u16*)(W + 5275648);              //  .. 5,276,160  (1024 u16)
    int*   adj   = (int*)(W + 5276160);              //  .. 5,538,304  (NN*MAXD ints)
    float* wadj  = W + 5538304;                      //  .. 5,800,448  (NN*MAXD)
    int*   cnt   = (int*)(W + 5800448);              //  .. 5,802,496  (NN ints)
    u16*   ctxb  = (u16*)(W + 5802496);              //  .. 6,326,784  (NN*DND u16)
    u16*   xupdb = (u16*)(W + 6326784);              //  .. 6,851,072  (NN*DND u16)
    u16*   sums  = (u16*)(W + 6851072);              //  .. 7,375,360  (NN*DND u16)
    u16*   nfb   = (u16*)(W + 7375360);              //  .. 7,899,648  (NN*DND u16)
    u16*   wbf   = (u16*)(W + 7899648);              //  .. 10,783,232 (5,767,168 u16)
    u16*   efbA  = (u16*)(W + 10783232);             //  .. 19,171,840 (EE*DND u16)
    u16*   efbB  = (u16*)(W + 19171840);             //  .. 27,560,448 (EE*DND u16)
    int*   table = (int*)efbA;                       //  alias: setup-only (16 MB < 32 MB)
    // total: 27,560,448 floats = 110.2 MB

    u16* inwb = wbf;
    u16* owb  = wbf + 1572864;
    u16* etwb = wbf + 2097152;
    u16* unwb = wbf + 2621440;
    u16* uewb = wbf + 3670016;

    float* out_nf = (float*)d_out;
    float* out_ef = out_nf + (size_t)NN * DND;

    const int* srcv = ei;
    const int* dstv = ei + EE;

    // setup: edge table, reverse-edge index, sparse-attention CSR (table aliases efbA; before conv)
    init_table_k<<<NN * NN / 256, 256, 0, stream>>>(table);
    fill_table_k<<<EE / 256, 256, 0, stream>>>(ei, table);
    build_rev_k<<<EE / 256, 256, 0, stream>>>(ei, table, rev);
    init_csr_k<<<NN / 256, 256, 0, stream>>>(adj, wadj, cnt);
    fill_csr_k<<<EE / 256, 256, 0, stream>>>(ei, rev, pos, adj, wadj, cnt);
    hipMemsetAsync(zero, 0, 2048, stream);

    // bf16 weight copies (both layers at once)
    conv_k<<<1572864 / 2048, 256, 0, stream>>>(inw, inwb);
    conv_k<<<524288 / 2048, 256, 0, stream>>>(ow, owb);
    conv_k<<<524288 / 2048, 256, 0, stream>>>(etw, etwb);
    conv_k<<<1048576 / 2048, 256, 0, stream>>>(unw, unwb);
    conv_k<<<2097152 / 2048, 256, 0, stream>>>(uew, uewb);
    // bf16 activations for layer 0
    conv_k<<<1048576 / 2048, 256, 0, stream>>>(x, nfb);
    conv_k<<<16777216 / 2048, 256, 0, stream>>>(efin, efbA);

    for (int l = 0; l < 2; ++l) {
        const u16* efb_cur = l ? efbB : efbA;
        const u16* inwb_l = inwb + (size_t)l * 786432;
        const u16* owb_l  = owb  + (size_t)l * 262144;
        const u16* etwb_l = etwb + (size_t)l * 262144;
        const u16* unwb_l = unwb + (size_t)l * 524288;
        const u16* uewb_l = uewb + (size_t)l * 1048576;
        const float* inb_l  = inb  + (size_t)l * 1536;
        const float* ob_l   = ob   + (size_t)l * 512;
        const float* etb_l  = etb  + (size_t)l * 512;
        const float* etg_l  = etg  + (size_t)l * 512;
        const float* etbb_l = etbb + (size_t)l * 512;
        const float* unb_l  = unb  + (size_t)l * 512;
        const float* ueb_l  = ueb  + (size_t)l * 512;

        // qkv = nf @ inw^T + inb   (f32 out for attention)
        mgemm_k<0, 0, 1, 0><<<dim3(16, 12), 256, 0, stream>>>(
            nfb, inwb_l, inb_l, qkv, nullptr, NN, 3 * DND, DND,
            nullptr, nullptr, nullptr, nullptr, nullptr, nullptr, nullptr, nullptr, nullptr, nullptr);

        // sparse masked MHSA -> ctx (bf16)
        attn_sp_k<<<dim3(NN, 2), 256, 0, stream>>>(qkv, adj, wadj, cnt, ctxb);

        // x_upd = ctx @ ow^T + ob  (bf16 out, only consumed by update_node gather)
        mgemm_k<0, 0, 0, 1><<<dim3(16, 4), 256, 0, stream>>>(
            ctxb, owb_l, ob_l, nullptr, xupdb, NN, DND, DND,
            nullptr, nullptr, nullptr, nullptr, nullptr, nullptr, nullptr, nullptr, nullptr, nullptr);

        // scatter-max accumulators
        hipMemsetAsync(subj, 0, (size_t)NN * DND * 4, stream);
        hipMemsetAsync(obj, 0, (size_t)NN * DND * 4, stream);

        // te = relu(BN(ef @ etw^T + etb)) with fused atomicMax scatter (no C write)
        mgemm_k<0, 2, 0, 0><<<dim3(256, 4), 256, 0, stream>>>(
            efb_cur, etwb_l, etb_l, nullptr, nullptr, EE, DND, DND,
            nullptr, nullptr, nullptr, srcv, dstv, nullptr, etg_l, etbb_l, subj, obj);

        // sumso = bf16(subj + obj)
        sumso_k<<<1048576 / 2048, 256, 0, stream>>>(subj, obj, sums);

        // ef_next = (relu?)([nf[src], ef, ef[rev], nf[dst]] @ uew^T + ueb)
        if (l == 0)
            mgemm_k<1, 1, 0, 1><<<dim3(256, 4), 256, 0, stream>>>(
                nullptr, uewb_l, ueb_l, nullptr, efbB, EE, DND, 2048,
                nfb, efb_cur, zero, srcv, dstv, rev, nullptr, nullptr, nullptr, nullptr);
        else
            mgemm_k<1, 0, 1, 0><<<dim3(256, 4), 256, 0, stream>>>(
                nullptr, uewb_l, ueb_l, out_ef, nullptr, EE, DND, 2048,
                nfb, efb_cur, zero, srcv, dstv, rev, nullptr, nullptr, nullptr, nullptr);

        // nf_next = (relu?)([x_upd, subj+obj] @ unw^T + unb)
        if (l == 0)
            mgemm_k<2, 1, 0, 1><<<dim3(16, 4), 256, 0, stream>>>(
                nullptr, unwb_l, unb_l, nullptr, nfb, NN, DND, 1024,
                xupdb, sums, nullptr, nullptr, nullptr, nullptr, nullptr, nullptr, nullptr, nullptr);
        else
            mgemm_k<2, 0, 1, 0><<<dim3(16, 4), 256, 0, stream>>>(
                nullptr, unwb_l, unb_l, out_nf, nullptr, NN, DND, 1024,
                xupdb, sums, nullptr, nullptr, nullptr, nullptr, nullptr, nullptr, nullptr, nullptr);
    }
}

// Round 5
// 827.621 us; speedup vs baseline: 5.3797x; 1.0140x over previous
//
#include <hip/hip_runtime.h>
#include <hip/hip_bf16.h>

#define NN 2048
#define EE 32768
#define DND 512
#define NH 8
#define HD 64
#define MAXD 128
#define NEGF (-1e30f)
#define BN_SCALE 0.9999950000374997f  // 1/sqrt(1+1e-5)

typedef __attribute__((ext_vector_type(8))) short bf16x8;
typedef __attribute__((ext_vector_type(4))) float f32x4;
typedef unsigned short u16;

static __device__ __forceinline__ float4 ld4(const float* p) {
    return *reinterpret_cast<const float4*>(p);
}
static __device__ __forceinline__ u16 f2b(float f) {
    __hip_bfloat16 h = __float2bfloat16(f);
    return *reinterpret_cast<u16*>(&h);
}
static __device__ __forceinline__ void gl_lds(const u16* g, u16* l) {
    __builtin_amdgcn_global_load_lds((const __attribute__((address_space(1))) void*)g,
                                     (__attribute__((address_space(3))) void*)l, 16, 0, 0);
}

// ---------------- setup kernels ----------------

__global__ __launch_bounds__(256) void init_table_k(int* __restrict__ t) {
    int i = blockIdx.x * 256 + threadIdx.x;
    t[i] = -1;
}

__global__ __launch_bounds__(256) void fill_table_k(const int* __restrict__ ei, int* __restrict__ t) {
    int e = blockIdx.x * 256 + threadIdx.x;
    if (e < EE) t[(size_t)ei[e] * NN + ei[EE + e]] = e;
}

__global__ __launch_bounds__(256) void build_rev_k(const int* __restrict__ ei, const int* __restrict__ t,
                                                   int* __restrict__ rev) {
    int e = blockIdx.x * 256 + threadIdx.x;
    if (e < EE) rev[e] = t[(size_t)ei[EE + e] * NN + ei[e]];
}

// CSR: slot 0 = self (weight 1.0), then neighbors
__global__ __launch_bounds__(256) void init_csr_k(int* __restrict__ adj, float* __restrict__ wadj,
                                                  int* __restrict__ cnt) {
    int i = blockIdx.x * 256 + threadIdx.x;
    if (i < NN) { cnt[i] = 1; adj[i * MAXD] = i; wadj[i * MAXD] = 1.0f; }
}

__global__ __launch_bounds__(256) void fill_csr_k(const int* __restrict__ ei, const int* __restrict__ rev,
                                                  const float* __restrict__ pos,
                                                  int* __restrict__ adj, float* __restrict__ wadj,
                                                  int* __restrict__ cnt) {
    int e = blockIdx.x * 256 + threadIdx.x;
    if (e >= EE) return;
    int s = ei[e], d = ei[EE + e];
    float dx = pos[s * 3 + 0] - pos[d * 3 + 0];
    float dy = pos[s * 3 + 1] - pos[d * 3 + 1];
    float dz = pos[s * 3 + 2] - pos[d * 3 + 2];
    float w = 1.0f / (sqrtf(dx * dx + dy * dy + dz * dz) + 1e-6f);
    int slot = atomicAdd(&cnt[s], 1);
    if (slot < MAXD) { adj[s * MAXD + slot] = d; wadj[s * MAXD + slot] = w; }
    if (rev[e] < 0) {  // symmetric pair not otherwise present -> add mirror
        slot = atomicAdd(&cnt[d], 1);
        if (slot < MAXD) { adj[d * MAXD + slot] = s; wadj[d * MAXD + slot] = w; }
    }
}

// ---------------- f32 -> bf16 conversion (8 elems/thread) ----------------
__global__ __launch_bounds__(256) void conv_k(const float* __restrict__ src, u16* __restrict__ dst) {
    int i = (blockIdx.x * 256 + threadIdx.x) * 8;
    float4 a = ld4(src + i), b = ld4(src + i + 4);
    u16 o[8];
    o[0] = f2b(a.x); o[1] = f2b(a.y); o[2] = f2b(a.z); o[3] = f2b(a.w);
    o[4] = f2b(b.x); o[5] = f2b(b.y); o[6] = f2b(b.z); o[7] = f2b(b.w);
    *reinterpret_cast<int4*>(dst + i) = *reinterpret_cast<const int4*>(o);
}

// sumso = bf16(subj + obj)
__global__ __launch_bounds__(256) void sumso_k(const float* __restrict__ s, const float* __restrict__ o,
                                               u16* __restrict__ dst) {
    int i = (blockIdx.x * 256 + threadIdx.x) * 8;
    float4 a = ld4(s + i), b = ld4(o + i), c = ld4(s + i + 4), d = ld4(o + i + 4);
    u16 ov[8];
    ov[0] = f2b(a.x + b.x); ov[1] = f2b(a.y + b.y); ov[2] = f2b(a.z + b.z); ov[3] = f2b(a.w + b.w);
    ov[4] = f2b(c.x + d.x); ov[5] = f2b(c.y + d.y); ov[6] = f2b(c.z + d.z); ov[7] = f2b(c.w + d.w);
    *reinterpret_cast<int4*>(dst + i) = *reinterpret_cast<const int4*>(ov);
}

// ---------------- MFMA GEMM: C[M,Nc] = epi(Agather[M,K](bf16) @ B[Nc,K](bf16)^T + bias) ----
// MODE 0: A plain row-major bf16 M x K
// MODE 1: A = [g0[src], g1, g1[rev]|zero, g0[dst]]   (K = 2048)
// MODE 2: A = [g0, g1]                               (K = 1024)
// EPI 0: +bias   EPI 1: relu(+bias)   EPI 2: relu((+bias)*BN_SCALE*eg+eb) + atomicMax scatter (no C write)
// LDS layout: [buf][kq 0..3][row 0..127][8 bf16]  -> conflict-free ds_read_b128 fragments
// 3-deep counted-vmcnt pipeline: stage t+2 each iter; loads for t+1/t+2 stay in
// flight across the barrier (vmcnt(8)); raw s_barrier, no full drain per iter.
template <int MODE, int EPI, int WF32, int WBF16>
__global__ __launch_bounds__(256) void mgemm_k(
    const u16* __restrict__ A, const u16* __restrict__ B, const float* __restrict__ bias,
    float* __restrict__ Cf, u16* __restrict__ Cb, int M, int Nc, int K,
    const u16* __restrict__ g0, const u16* __restrict__ g1, const u16* __restrict__ gz,
    const int* __restrict__ srcv, const int* __restrict__ dstv, const int* __restrict__ revv,
    const float* __restrict__ eg, const float* __restrict__ eb,
    float* __restrict__ subj, float* __restrict__ obj)
{
    __shared__ u16 As2[3][4096];
    __shared__ u16 Bs2[3][4096];
    const int tid = threadIdx.x, lane = tid & 63, w = tid >> 6;
    const int wr = w >> 1, wc = w & 1;
    const int bm = blockIdx.x * 128, bn = blockIdx.y * 128;

    const u16* pa0[2];
    const u16* pa1[2];
    const u16* pa2[2];
    const u16* pa3[2];
    const u16* pb[2];
#pragma unroll
    for (int h = 0; h < 2; ++h) {
        const int r = bm + h * 64 + lane;
        if (MODE == 0) {
            pa0[h] = A + (size_t)r * K + w * 8;
        } else if (MODE == 1) {
            pa0[h] = g0 + (size_t)srcv[r] * DND + w * 8;
            pa1[h] = g1 + (size_t)r * DND + w * 8;
            const int rv = revv[r];
            pa2[h] = (rv >= 0) ? (g1 + (size_t)rv * DND + w * 8) : (gz + w * 8);
            pa3[h] = g0 + (size_t)dstv[r] * DND + w * 8;
        } else {
            pa0[h] = g0 + (size_t)r * DND + w * 8;
            pa1[h] = g1 + (size_t)r * DND + w * 8;
        }
        pb[h] = B + (size_t)(bn + h * 64 + lane) * K + w * 8;
    }

    const int nks = K >> 5;
    const int kq = lane >> 4, li = lane & 15;

    auto stage = [&](int t, int b) {
        const int k0 = t * 32;
        const u16* ga0;
        const u16* ga1;
        if (MODE == 0) {
            ga0 = pa0[0] + k0; ga1 = pa0[1] + k0;
        } else if (MODE == 1) {
            const int seg = k0 >> 9, koff = k0 & 511;
            ga0 = (seg == 0 ? pa0[0] : seg == 1 ? pa1[0] : seg == 2 ? pa2[0] : pa3[0]) + koff;
            ga1 = (seg == 0 ? pa0[1] : seg == 1 ? pa1[1] : seg == 2 ? pa2[1] : pa3[1]) + koff;
        } else {
            const int seg = k0 >> 9, koff = k0 & 511;
            ga0 = (seg == 0 ? pa0[0] : pa1[0]) + koff;
            ga1 = (seg == 0 ? pa0[1] : pa1[1]) + koff;
        }
        gl_lds(ga0, &As2[b][w * 1024]);
        gl_lds(ga1, &As2[b][w * 1024 + 512]);
        gl_lds(pb[0] + k0, &Bs2[b][w * 1024]);
        gl_lds(pb[1] + k0, &Bs2[b][w * 1024 + 512]);
    };

    f32x4 acc[4][4] = {};
    stage(0, 0);
    stage(1, 1);
    for (int t = 0; t < nks; ++t) {
        const int cur = t % 3;
        if (t + 2 < nks) stage(t + 2, (t + 2) % 3);
        // wait until tile t's 4 loads have landed; keep t+1/t+2 (8 loads) in flight
        if (t + 2 < nks)      asm volatile("s_waitcnt vmcnt(8)" ::: "memory");
        else if (t + 1 < nks) asm volatile("s_waitcnt vmcnt(4)" ::: "memory");
        else                  asm volatile("s_waitcnt vmcnt(0)" ::: "memory");
        __builtin_amdgcn_s_barrier();
        __builtin_amdgcn_sched_barrier(0);
        bf16x8 af[4], bf[4];
#pragma unroll
        for (int m = 0; m < 4; ++m)
            af[m] = *reinterpret_cast<const bf16x8*>(&As2[cur][kq * 1024 + (wr * 64 + m * 16 + li) * 8]);
#pragma unroll
        for (int n = 0; n < 4; ++n)
            bf[n] = *reinterpret_cast<const bf16x8*>(&Bs2[cur][kq * 1024 + (wc * 64 + n * 16 + li) * 8]);
#pragma unroll
        for (int m = 0; m < 4; ++m)
#pragma unroll
            for (int n = 0; n < 4; ++n)
                acc[m][n] = __builtin_amdgcn_mfma_f32_16x16x32_bf16(af[m], bf[n], acc[m][n], 0, 0, 0);
        // all waves done reading buf[cur] before iter t+1 stages into it
        __builtin_amdgcn_s_barrier();
        __builtin_amdgcn_sched_barrier(0);
    }

    float bsv[4], scv[4], shv[4];
#pragma unroll
    for (int n = 0; n < 4; ++n) {
        const int col = bn + wc * 64 + n * 16 + li;
        bsv[n] = bias[col];
        if (EPI == 2) { scv[n] = BN_SCALE * eg[col]; shv[n] = eb[col]; }
    }
#pragma unroll
    for (int m = 0; m < 4; ++m) {
        int se[4], de[4];
        if (EPI == 2) {
#pragma unroll
            for (int i = 0; i < 4; ++i) {
                const int r = bm + wr * 64 + m * 16 + (lane >> 4) * 4 + i;
                se[i] = srcv[r]; de[i] = dstv[r];
            }
        }
#pragma unroll
        for (int n = 0; n < 4; ++n) {
            const int col = bn + wc * 64 + n * 16 + li;
#pragma unroll
            for (int i = 0; i < 4; ++i) {
                float v = acc[m][n][i] + bsv[n];
                if (EPI == 2) {
                    v = fmaxf(fmaf(v, scv[n], shv[n]), 0.f);
                    const unsigned uv = __float_as_uint(v);
                    atomicMax(reinterpret_cast<unsigned*>(subj) + (size_t)se[i] * DND + col, uv);
                    atomicMax(reinterpret_cast<unsigned*>(obj) + (size_t)de[i] * DND + col, uv);
                } else {
                    if (EPI == 1) v = fmaxf(v, 0.f);
                    const int r = bm + wr * 64 + m * 16 + (lane >> 4) * 4 + i;
                    if (WF32) Cf[(size_t)r * Nc + col] = v;
                    if (WBF16) Cb[(size_t)r * Nc + col] = f2b(v);
                }
            }
        }
    }
}

// ---------------- sparse attention: 1 wave per (node, head) ----------------
__global__ __launch_bounds__(256) void attn_sp_k(const float* __restrict__ qkv,
                                                 const int* __restrict__ adj,
                                                 const float* __restrict__ wadj,
                                                 const int* __restrict__ cnt,
                                                 u16* __restrict__ ctxb)
{
    const int i = blockIdx.x;
    const int wv = threadIdx.x >> 6, lane = threadIdx.x & 63;
    const int h = blockIdx.y * 4 + wv;
    __shared__ float qs[4][64];
    qs[wv][lane] = qkv[(size_t)i * 1536 + h * HD + lane] * 0.125f;  // 1/sqrt(64)
    __syncthreads();
    int deg = cnt[i];
    if (deg > MAXD) deg = MAXD;
    float m = -3.0e38f, lsum = 0.f, c = 0.f;
    for (int base = 0; base < deg; base += 64) {
        int nn_ = deg - base; if (nn_ > 64) nn_ = 64;
        int j = 0;
        float s = NEGF;
        if (lane < nn_) {
            j = adj[i * MAXD + base + lane];
            const float wgt = wadj[i * MAXD + base + lane];
            const float* kr = qkv + (size_t)j * 1536 + DND + h * HD;
            float accd = 0.f;
#pragma unroll
            for (int d4 = 0; d4 < 16; ++d4) {
                float4 kv = ld4(kr + d4 * 4);
                accd = fmaf(qs[wv][d4 * 4 + 0], kv.x, accd);
                accd = fmaf(qs[wv][d4 * 4 + 1], kv.y, accd);
                accd = fmaf(qs[wv][d4 * 4 + 2], kv.z, accd);
                accd = fmaf(qs[wv][d4 * 4 + 3], kv.w, accd);
            }
            s = accd + wgt;
        }
        float mloc = s;
#pragma unroll
        for (int o = 1; o < 64; o <<= 1) mloc = fmaxf(mloc, __shfl_xor(mloc, o, 64));
        const float mnew = fmaxf(m, mloc);
        const float alpha = __expf(m - mnew);
        const float p = (lane < nn_) ? __expf(s - mnew) : 0.f;
        float ps = p;
#pragma unroll
        for (int o = 1; o < 64; o <<= 1) ps += __shfl_xor(ps, o, 64);
        lsum = lsum * alpha + ps;
        c *= alpha;
        for (int l = 0; l < nn_; ++l) {
            const float pj = __shfl(p, l, 64);
            const int jj = __shfl(j, l, 64);
            c = fmaf(pj, qkv[(size_t)jj * 1536 + 2 * DND + h * HD + lane], c);
        }
        m = mnew;
    }
    ctxb[(size_t)i * DND + h * HD + lane] = f2b(c / lsum);
}

// ---------------- host orchestration ----------------
extern "C" void kernel_launch(void* const* d_in, const int* in_sizes, int n_in,
                              void* d_out, int out_size, void* d_ws, size_t ws_size,
                              hipStream_t stream)
{
    const float* x    = (const float*)d_in[0];
    const float* efin = (const float*)d_in[1];
    const float* pos  = (const float*)d_in[2];
    const float* inw  = (const float*)d_in[3];
    const float* inb  = (const float*)d_in[4];
    const float* ow   = (const float*)d_in[5];
    const float* ob   = (const float*)d_in[6];
    const float* etw  = (const float*)d_in[7];
    const float* etb  = (const float*)d_in[8];
    const float* etg  = (const float*)d_in[9];
    const float* etbb = (const float*)d_in[10];
    const float* unw  = (const float*)d_in[11];
    const float* unb  = (const float*)d_in[12];
    const float* uew  = (const float*)d_in[13];
    const float* ueb  = (const float*)d_in[14];
    const int*   ei   = (const int*)d_in[15];

    // workspace layout (offsets in floats)
    float* W = (float*)d_ws;
    float* qkv   = W;                                //          0 .. 3,145,728  (NN*3*DND)
    float* subj  = W + 3145728;                      //  3,145,728 .. 4,194,304  (NN*DND)
    float* obj   = W + 4194304;                      //  4,194,304 .. 5,242,880  (NN*DND)
    int*   rev   = (int*)(W + 5242880);              //  .. 5,275,648  (EE ints)
    u16*   zero  = (u16*)(W + 5275648);              //  .. 5,276,160  (1024 u16)
    int*   adj   = (int*)(W + 5276160);              //  .. 5,538,304  (NN*MAXD ints)
    float* wadj  = W + 5538304;                      //  .. 5,800,448  (NN*MAXD)
    int*   cnt   = (int*)(W + 5800448);              //  .. 5,802,496  (NN ints)
    u16*   ctxb  = (u16*)(W + 5802496);              //  .. 6,326,784  (NN*DND u16)
    u16*   xupdb = (u16*)(W + 6326784);              //  .. 6,851,072  (NN*DND u16)
    u16*   sums  = (u16*)(W + 6851072);              //  .. 7,375,360  (NN*DND u16)
    u16*   nfb   = (u16*)(W + 7375360);              //  .. 7,899,648  (NN*DND u16)
    u16*   wbf   = (u16*)(W + 7899648);              //  .. 10,783,232 (5,767,168 u16)
    u16*   efbA  = (u16*)(W + 10783232);             //  .. 19,171,840 (EE*DND u16)
    u16*   efbB  = (u16*)(W + 19171840);             //  .. 27,560,448 (EE*DND u16)
    int*   table = (int*)efbA;                       //  alias: setup-only (16 MB < 32 MB)
    // total: 27,560,448 floats = 110.2 MB

    u16* inwb = wbf;
    u16* owb  = wbf + 1572864;
    u16* etwb = wbf + 2097152;
    u16* unwb = wbf + 2621440;
    u16* uewb = wbf + 3670016;

    float* out_nf = (float*)d_out;
    float* out_ef = out_nf + (size_t)NN * DND;

    const int* srcv = ei;
    const int* dstv = ei + EE;

    // setup: edge table, reverse-edge index, sparse-attention CSR (table aliases efbA; before conv)
    init_table_k<<<NN * NN / 256, 256, 0, stream>>>(table);
    fill_table_k<<<EE / 256, 256, 0, stream>>>(ei, table);
    build_rev_k<<<EE / 256, 256, 0, stream>>>(ei, table, rev);
    init_csr_k<<<NN / 256, 256, 0, stream>>>(adj, wadj, cnt);
    fill_csr_k<<<EE / 256, 256, 0, stream>>>(ei, rev, pos, adj, wadj, cnt);
    hipMemsetAsync(zero, 0, 2048, stream);

    // bf16 weight copies (both layers at once)
    conv_k<<<1572864 / 2048, 256, 0, stream>>>(inw, inwb);
    conv_k<<<524288 / 2048, 256, 0, stream>>>(ow, owb);
    conv_k<<<524288 / 2048, 256, 0, stream>>>(etw, etwb);
    conv_k<<<1048576 / 2048, 256, 0, stream>>>(unw, unwb);
    conv_k<<<2097152 / 2048, 256, 0, stream>>>(uew, uewb);
    // bf16 activations for layer 0
    conv_k<<<1048576 / 2048, 256, 0, stream>>>(x, nfb);
    conv_k<<<16777216 / 2048, 256, 0, stream>>>(efin, efbA);

    for (int l = 0; l < 2; ++l) {
        const u16* efb_cur = l ? efbB : efbA;
        const u16* inwb_l = inwb + (size_t)l * 786432;
        const u16* owb_l  = owb  + (size_t)l * 262144;
        const u16* etwb_l = etwb + (size_t)l * 262144;
        const u16* unwb_l = unwb + (size_t)l * 524288;
        const u16* uewb_l = uewb + (size_t)l * 1048576;
        const float* inb_l  = inb  + (size_t)l * 1536;
        const float* ob_l   = ob   + (size_t)l * 512;
        const float* etb_l  = etb  + (size_t)l * 512;
        const float* etg_l  = etg  + (size_t)l * 512;
        const float* etbb_l = etbb + (size_t)l * 512;
        const float* unb_l  = unb  + (size_t)l * 512;
        const float* ueb_l  = ueb  + (size_t)l * 512;

        // qkv = nf @ inw^T + inb   (f32 out for attention)
        mgemm_k<0, 0, 1, 0><<<dim3(16, 12), 256, 0, stream>>>(
            nfb, inwb_l, inb_l, qkv, nullptr, NN, 3 * DND, DND,
            nullptr, nullptr, nullptr, nullptr, nullptr, nullptr, nullptr, nullptr, nullptr, nullptr);

        // sparse masked MHSA -> ctx (bf16)
        attn_sp_k<<<dim3(NN, 2), 256, 0, stream>>>(qkv, adj, wadj, cnt, ctxb);

        // x_upd = ctx @ ow^T + ob  (bf16 out, only consumed by update_node gather)
        mgemm_k<0, 0, 0, 1><<<dim3(16, 4), 256, 0, stream>>>(
            ctxb, owb_l, ob_l, nullptr, xupdb, NN, DND, DND,
            nullptr, nullptr, nullptr, nullptr, nullptr, nullptr, nullptr, nullptr, nullptr, nullptr);

        // scatter-max accumulators (subj+obj are adjacent -> one memset)
        hipMemsetAsync(subj, 0, (size_t)2 * NN * DND * 4, stream);

        // te = relu(BN(ef @ etw^T + etb)) with fused atomicMax scatter (no C write)
        mgemm_k<0, 2, 0, 0><<<dim3(256, 4), 256, 0, stream>>>(
            efb_cur, etwb_l, etb_l, nullptr, nullptr, EE, DND, DND,
            nullptr, nullptr, nullptr, srcv, dstv, nullptr, etg_l, etbb_l, subj, obj);

        // sumso = bf16(subj + obj)
        sumso_k<<<1048576 / 2048, 256, 0, stream>>>(subj, obj, sums);

        // ef_next = (relu?)([nf[src], ef, ef[rev], nf[dst]] @ uew^T + ueb)
        if (l == 0)
            mgemm_k<1, 1, 0, 1><<<dim3(256, 4), 256, 0, stream>>>(
                nullptr, uewb_l, ueb_l, nullptr, efbB, EE, DND, 2048,
                nfb, efb_cur, zero, srcv, dstv, rev, nullptr, nullptr, nullptr, nullptr);
        else
            mgemm_k<1, 0, 1, 0><<<dim3(256, 4), 256, 0, stream>>>(
                nullptr, uewb_l, ueb_l, out_ef, nullptr, EE, DND, 2048,
                nfb, efb_cur, zero, srcv, dstv, rev, nullptr, nullptr, nullptr, nullptr);

        // nf_next = (relu?)([x_upd, subj+obj] @ unw^T + unb)
        if (l == 0)
            mgemm_k<2, 1, 0, 1><<<dim3(16, 4), 256, 0, stream>>>(
                nullptr, unwb_l, unb_l, nullptr, nfb, NN, DND, 1024,
                xupdb, sums, nullptr, nullptr, nullptr, nullptr, nullptr, nullptr, nullptr, nullptr);
        else
            mgemm_k<2, 0, 1, 0><<<dim3(16, 4), 256, 0, stream>>>(
                nullptr, unwb_l, unb_l, out_nf, nullptr, NN, DND, 1024,
                xupdb, sums, nullptr, nullptr, nullptr, nullptr, nullptr, nullptr, nullptr, nullptr);
    }
}

// Round 6
// 805.881 us; speedup vs baseline: 5.5249x; 1.0270x over previous
//
#include <hip/hip_runtime.h>
#include <hip/hip_bf16.h>

#define NN 2048
#define EE 32768
#define DND 512
#define NH 8
#define HD 64
#define MAXD 128
#define NEGF (-1e30f)
#define BN_SCALE 0.9999950000374997f  // 1/sqrt(1+1e-5)

typedef __attribute__((ext_vector_type(8))) short bf16x8;
typedef __attribute__((ext_vector_type(4))) float f32x4;
typedef unsigned short u16;

static __device__ __forceinline__ float4 ld4(const float* p) {
    return *reinterpret_cast<const float4*>(p);
}
static __device__ __forceinline__ u16 f2b(float f) {
    __hip_bfloat16 h = __float2bfloat16(f);
    return *reinterpret_cast<u16*>(&h);
}
static __device__ __forceinline__ void gl_lds(const u16* g, u16* l) {
    __builtin_amdgcn_global_load_lds((const __attribute__((address_space(1))) void*)g,
                                     (__attribute__((address_space(3))) void*)l, 16, 0, 0);
}

// ---------------- setup kernels ----------------

__global__ __launch_bounds__(256) void init_table_k(int* __restrict__ t) {
    int i = blockIdx.x * 256 + threadIdx.x;
    t[i] = -1;
}

__global__ __launch_bounds__(256) void fill_table_k(const int* __restrict__ ei, int* __restrict__ t) {
    int e = blockIdx.x * 256 + threadIdx.x;
    if (e < EE) t[(size_t)ei[e] * NN + ei[EE + e]] = e;
}

__global__ __launch_bounds__(256) void build_rev_k(const int* __restrict__ ei, const int* __restrict__ t,
                                                   int* __restrict__ rev) {
    int e = blockIdx.x * 256 + threadIdx.x;
    if (e < EE) rev[e] = t[(size_t)ei[EE + e] * NN + ei[e]];
}

// CSR: slot 0 = self (weight 1.0), then neighbors
__global__ __launch_bounds__(256) void init_csr_k(int* __restrict__ adj, float* __restrict__ wadj,
                                                  int* __restrict__ cnt) {
    int i = blockIdx.x * 256 + threadIdx.x;
    if (i < NN) { cnt[i] = 1; adj[i * MAXD] = i; wadj[i * MAXD] = 1.0f; }
}

__global__ __launch_bounds__(256) void fill_csr_k(const int* __restrict__ ei, const int* __restrict__ rev,
                                                  const float* __restrict__ pos,
                                                  int* __restrict__ adj, float* __restrict__ wadj,
                                                  int* __restrict__ cnt) {
    int e = blockIdx.x * 256 + threadIdx.x;
    if (e >= EE) return;
    int s = ei[e], d = ei[EE + e];
    float dx = pos[s * 3 + 0] - pos[d * 3 + 0];
    float dy = pos[s * 3 + 1] - pos[d * 3 + 1];
    float dz = pos[s * 3 + 2] - pos[d * 3 + 2];
    float w = 1.0f / (sqrtf(dx * dx + dy * dy + dz * dz) + 1e-6f);
    int slot = atomicAdd(&cnt[s], 1);
    if (slot < MAXD) { adj[s * MAXD + slot] = d; wadj[s * MAXD + slot] = w; }
    if (rev[e] < 0) {  // symmetric pair not otherwise present -> add mirror
        slot = atomicAdd(&cnt[d], 1);
        if (slot < MAXD) { adj[d * MAXD + slot] = s; wadj[d * MAXD + slot] = w; }
    }
}

// ---------------- f32 -> bf16 conversion (8 elems/thread) ----------------
__global__ __launch_bounds__(256) void conv_k(const float* __restrict__ src, u16* __restrict__ dst) {
    int i = (blockIdx.x * 256 + threadIdx.x) * 8;
    float4 a = ld4(src + i), b = ld4(src + i + 4);
    u16 o[8];
    o[0] = f2b(a.x); o[1] = f2b(a.y); o[2] = f2b(a.z); o[3] = f2b(a.w);
    o[4] = f2b(b.x); o[5] = f2b(b.y); o[6] = f2b(b.z); o[7] = f2b(b.w);
    *reinterpret_cast<int4*>(dst + i) = *reinterpret_cast<const int4*>(o);
}

// sumso = bf16(subj + obj)
__global__ __launch_bounds__(256) void sumso_k(const float* __restrict__ s, const float* __restrict__ o,
                                               u16* __restrict__ dst) {
    int i = (blockIdx.x * 256 + threadIdx.x) * 8;
    float4 a = ld4(s + i), b = ld4(o + i), c = ld4(s + i + 4), d = ld4(o + i + 4);
    u16 ov[8];
    ov[0] = f2b(a.x + b.x); ov[1] = f2b(a.y + b.y); ov[2] = f2b(a.z + b.z); ov[3] = f2b(a.w + b.w);
    ov[4] = f2b(c.x + d.x); ov[5] = f2b(c.y + d.y); ov[6] = f2b(c.z + d.z); ov[7] = f2b(c.w + d.w);
    *reinterpret_cast<int4*>(dst + i) = *reinterpret_cast<const int4*>(ov);
}

// ---------------- MFMA GEMM: C[M,Nc] = epi(Agather[M,K](bf16) @ B[Nc,K](bf16)^T + bias) ----
// MODE 0: A plain row-major bf16 M x K
// MODE 1: A = [g0[src], g1, g1[rev]|zero, g0[dst]]   (K = 2048)
// MODE 2: A = [g0, g1]                               (K = 1024)
// EPI 0: +bias   EPI 1: relu(+bias)   EPI 2: relu((+bias)*BN_SCALE*eg+eb) + atomicMax scatter (no C write)
// 1-D grid of GX*GY blocks with XCD temporal-locality swizzle: the GY col-blocks
// sharing one A-tile get hw ids 8 apart (same XCD under %8 round-robin) and are
// dispatched within a 8*GY window -> A-tile re-reads hit that XCD's L2 instead
// of re-pulling from L3 (the R5 bottleneck).
// LDS layout: [buf][kq 0..3][row 0..127][8 bf16]  -> conflict-free ds_read_b128 fragments
// 3-deep counted-vmcnt pipeline: stage t+2 each iter; t+1/t+2 loads stay in flight.
template <int MODE, int EPI, int WF32, int WBF16, int GY>
__global__ __launch_bounds__(256) void mgemm_k(
    const u16* __restrict__ A, const u16* __restrict__ B, const float* __restrict__ bias,
    float* __restrict__ Cf, u16* __restrict__ Cb, int M, int Nc, int K,
    const u16* __restrict__ g0, const u16* __restrict__ g1, const u16* __restrict__ gz,
    const int* __restrict__ srcv, const int* __restrict__ dstv, const int* __restrict__ revv,
    const float* __restrict__ eg, const float* __restrict__ eb,
    float* __restrict__ subj, float* __restrict__ obj)
{
    __shared__ u16 As2[3][4096];
    __shared__ u16 Bs2[3][4096];
    const int tid = threadIdx.x, lane = tid & 63, w = tid >> 6;
    const int wr = w >> 1, wc = w & 1;
    // swizzle: b = (xcd, kb); col = kb % GY (fast), rowblk = (kb / GY)*8 + xcd
    const int b = blockIdx.x;
    const int xcd = b & 7, kb = b >> 3;
    const int bm = ((kb / GY) * 8 + xcd) * 128;
    const int bn = (kb % GY) * 128;

    const u16* pa0[2];
    const u16* pa1[2];
    const u16* pa2[2];
    const u16* pa3[2];
    const u16* pb[2];
#pragma unroll
    for (int h = 0; h < 2; ++h) {
        const int r = bm + h * 64 + lane;
        if (MODE == 0) {
            pa0[h] = A + (size_t)r * K + w * 8;
        } else if (MODE == 1) {
            pa0[h] = g0 + (size_t)srcv[r] * DND + w * 8;
            pa1[h] = g1 + (size_t)r * DND + w * 8;
            const int rv = revv[r];
            pa2[h] = (rv >= 0) ? (g1 + (size_t)rv * DND + w * 8) : (gz + w * 8);
            pa3[h] = g0 + (size_t)dstv[r] * DND + w * 8;
        } else {
            pa0[h] = g0 + (size_t)r * DND + w * 8;
            pa1[h] = g1 + (size_t)r * DND + w * 8;
        }
        pb[h] = B + (size_t)(bn + h * 64 + lane) * K + w * 8;
    }

    const int nks = K >> 5;
    const int kq = lane >> 4, li = lane & 15;

    auto stage = [&](int t, int bb) {
        const int k0 = t * 32;
        const u16* ga0;
        const u16* ga1;
        if (MODE == 0) {
            ga0 = pa0[0] + k0; ga1 = pa0[1] + k0;
        } else if (MODE == 1) {
            const int seg = k0 >> 9, koff = k0 & 511;
            ga0 = (seg == 0 ? pa0[0] : seg == 1 ? pa1[0] : seg == 2 ? pa2[0] : pa3[0]) + koff;
            ga1 = (seg == 0 ? pa0[1] : seg == 1 ? pa1[1] : seg == 2 ? pa2[1] : pa3[1]) + koff;
        } else {
            const int seg = k0 >> 9, koff = k0 & 511;
            ga0 = (seg == 0 ? pa0[0] : pa1[0]) + koff;
            ga1 = (seg == 0 ? pa0[1] : pa1[1]) + koff;
        }
        gl_lds(ga0, &As2[bb][w * 1024]);
        gl_lds(ga1, &As2[bb][w * 1024 + 512]);
        gl_lds(pb[0] + k0, &Bs2[bb][w * 1024]);
        gl_lds(pb[1] + k0, &Bs2[bb][w * 1024 + 512]);
    };

    f32x4 acc[4][4] = {};
    stage(0, 0);
    stage(1, 1);
    for (int t = 0; t < nks; ++t) {
        const int cur = t % 3;
        if (t + 2 < nks) stage(t + 2, (t + 2) % 3);
        // wait until tile t's 4 loads have landed; keep t+1/t+2 (8 loads) in flight
        if (t + 2 < nks)      asm volatile("s_waitcnt vmcnt(8)" ::: "memory");
        else if (t + 1 < nks) asm volatile("s_waitcnt vmcnt(4)" ::: "memory");
        else                  asm volatile("s_waitcnt vmcnt(0)" ::: "memory");
        __builtin_amdgcn_s_barrier();
        __builtin_amdgcn_sched_barrier(0);
        bf16x8 af[4], bf[4];
#pragma unroll
        for (int m = 0; m < 4; ++m)
            af[m] = *reinterpret_cast<const bf16x8*>(&As2[cur][kq * 1024 + (wr * 64 + m * 16 + li) * 8]);
#pragma unroll
        for (int n = 0; n < 4; ++n)
            bf[n] = *reinterpret_cast<const bf16x8*>(&Bs2[cur][kq * 1024 + (wc * 64 + n * 16 + li) * 8]);
#pragma unroll
        for (int m = 0; m < 4; ++m)
#pragma unroll
            for (int n = 0; n < 4; ++n)
                acc[m][n] = __builtin_amdgcn_mfma_f32_16x16x32_bf16(af[m], bf[n], acc[m][n], 0, 0, 0);
        // all waves done reading buf[cur] before iter t+1 stages into it
        __builtin_amdgcn_s_barrier();
        __builtin_amdgcn_sched_barrier(0);
    }

    float bsv[4], scv[4], shv[4];
#pragma unroll
    for (int n = 0; n < 4; ++n) {
        const int col = bn + wc * 64 + n * 16 + li;
        bsv[n] = bias[col];
        if (EPI == 2) { scv[n] = BN_SCALE * eg[col]; shv[n] = eb[col]; }
    }
#pragma unroll
    for (int m = 0; m < 4; ++m) {
        int se[4], de[4];
        if (EPI == 2) {
#pragma unroll
            for (int i = 0; i < 4; ++i) {
                const int r = bm + wr * 64 + m * 16 + (lane >> 4) * 4 + i;
                se[i] = srcv[r]; de[i] = dstv[r];
            }
        }
#pragma unroll
        for (int n = 0; n < 4; ++n) {
            const int col = bn + wc * 64 + n * 16 + li;
#pragma unroll
            for (int i = 0; i < 4; ++i) {
                float v = acc[m][n][i] + bsv[n];
                if (EPI == 2) {
                    v = fmaxf(fmaf(v, scv[n], shv[n]), 0.f);
                    const unsigned uv = __float_as_uint(v);
                    atomicMax(reinterpret_cast<unsigned*>(subj) + (size_t)se[i] * DND + col, uv);
                    atomicMax(reinterpret_cast<unsigned*>(obj) + (size_t)de[i] * DND + col, uv);
                } else {
                    if (EPI == 1) v = fmaxf(v, 0.f);
                    const int r = bm + wr * 64 + m * 16 + (lane >> 4) * 4 + i;
                    if (WF32) Cf[(size_t)r * Nc + col] = v;
                    if (WBF16) Cb[(size_t)r * Nc + col] = f2b(v);
                }
            }
        }
    }
}

// ---------------- sparse attention: 1 wave per (node, head) ----------------
__global__ __launch_bounds__(256) void attn_sp_k(const float* __restrict__ qkv,
                                                 const int* __restrict__ adj,
                                                 const float* __restrict__ wadj,
                                                 const int* __restrict__ cnt,
                                                 u16* __restrict__ ctxb)
{
    const int i = blockIdx.x;
    const int wv = threadIdx.x >> 6, lane = threadIdx.x & 63;
    const int h = blockIdx.y * 4 + wv;
    __shared__ float qs[4][64];
    qs[wv][lane] = qkv[(size_t)i * 1536 + h * HD + lane] * 0.125f;  // 1/sqrt(64)
    __syncthreads();
    int deg = cnt[i];
    if (deg > MAXD) deg = MAXD;
    float m = -3.0e38f, lsum = 0.f, c = 0.f;
    for (int base = 0; base < deg; base += 64) {
        int nn_ = deg - base; if (nn_ > 64) nn_ = 64;
        int j = 0;
        float s = NEGF;
        if (lane < nn_) {
            j = adj[i * MAXD + base + lane];
            const float wgt = wadj[i * MAXD + base + lane];
            const float* kr = qkv + (size_t)j * 1536 + DND + h * HD;
            float accd = 0.f;
#pragma unroll
            for (int d4 = 0; d4 < 16; ++d4) {
                float4 kv = ld4(kr + d4 * 4);
                accd = fmaf(qs[wv][d4 * 4 + 0], kv.x, accd);
                accd = fmaf(qs[wv][d4 * 4 + 1], kv.y, accd);
                accd = fmaf(qs[wv][d4 * 4 + 2], kv.z, accd);
                accd = fmaf(qs[wv][d4 * 4 + 3], kv.w, accd);
            }
            s = accd + wgt;
        }
        float mloc = s;
#pragma unroll
        for (int o = 1; o < 64; o <<= 1) mloc = fmaxf(mloc, __shfl_xor(mloc, o, 64));
        const float mnew = fmaxf(m, mloc);
        const float alpha = __expf(m - mnew);
        const float p = (lane < nn_) ? __expf(s - mnew) : 0.f;
        float ps = p;
#pragma unroll
        for (int o = 1; o < 64; o <<= 1) ps += __shfl_xor(ps, o, 64);
        lsum = lsum * alpha + ps;
        c *= alpha;
        for (int l = 0; l < nn_; ++l) {
            const float pj = __shfl(p, l, 64);
            const int jj = __shfl(j, l, 64);
            c = fmaf(pj, qkv[(size_t)jj * 1536 + 2 * DND + h * HD + lane], c);
        }
        m = mnew;
    }
    ctxb[(size_t)i * DND + h * HD + lane] = f2b(c / lsum);
}

// ---------------- host orchestration ----------------
extern "C" void kernel_launch(void* const* d_in, const int* in_sizes, int n_in,
                              void* d_out, int out_size, void* d_ws, size_t ws_size,
                              hipStream_t stream)
{
    const float* x    = (const float*)d_in[0];
    const float* efin = (const float*)d_in[1];
    const float* pos  = (const float*)d_in[2];
    const float* inw  = (const float*)d_in[3];
    const float* inb  = (const float*)d_in[4];
    const float* ow   = (const float*)d_in[5];
    const float* ob   = (const float*)d_in[6];
    const float* etw  = (const float*)d_in[7];
    const float* etb  = (const float*)d_in[8];
    const float* etg  = (const float*)d_in[9];
    const float* etbb = (const float*)d_in[10];
    const float* unw  = (const float*)d_in[11];
    const float* unb  = (const float*)d_in[12];
    const float* uew  = (const float*)d_in[13];
    const float* ueb  = (const float*)d_in[14];
    const int*   ei   = (const int*)d_in[15];

    // workspace layout (offsets in floats)
    float* W = (float*)d_ws;
    float* qkv   = W;                                //          0 .. 3,145,728  (NN*3*DND)
    float* subj  = W + 3145728;                      //  3,145,728 .. 4,194,304  (NN*DND)
    float* obj   = W + 4194304;                      //  4,194,304 .. 5,242,880  (NN*DND)
    int*   rev   = (int*)(W + 5242880);              //  .. 5,275,648  (EE ints)
    u16*   zero  = (u16*)(W + 5275648);              //  .. 5,276,160  (1024 u16)
    int*   adj   = (int*)(W + 5276160);              //  .. 5,538,304  (NN*MAXD ints)
    float* wadj  = W + 5538304;                      //  .. 5,800,448  (NN*MAXD)
    int*   cnt   = (int*)(W + 5800448);              //  .. 5,802,496  (NN ints)
    u16*   ctxb  = (u16*)(W + 5802496);              //  .. 6,326,784  (NN*DND u16)
    u16*   xupdb = (u16*)(W + 6326784);              //  .. 6,851,072  (NN*DND u16)
    u16*   sums  = (u16*)(W + 6851072);              //  .. 7,375,360  (NN*DND u16)
    u16*   nfb   = (u16*)(W + 7375360);              //  .. 7,899,648  (NN*DND u16)
    u16*   wbf   = (u16*)(W + 7899648);              //  .. 10,783,232 (5,767,168 u16)
    u16*   efbA  = (u16*)(W + 10783232);             //  .. 19,171,840 (EE*DND u16)
    u16*   efbB  = (u16*)(W + 19171840);             //  .. 27,560,448 (EE*DND u16)
    int*   table = (int*)efbA;                       //  alias: setup-only (16 MB < 32 MB)
    // total: 27,560,448 floats = 110.2 MB

    u16* inwb = wbf;
    u16* owb  = wbf + 1572864;
    u16* etwb = wbf + 2097152;
    u16* unwb = wbf + 2621440;
    u16* uewb = wbf + 3670016;

    float* out_nf = (float*)d_out;
    float* out_ef = out_nf + (size_t)NN * DND;

    const int* srcv = ei;
    const int* dstv = ei + EE;

    // setup: edge table, reverse-edge index, sparse-attention CSR (table aliases efbA; before conv)
    init_table_k<<<NN * NN / 256, 256, 0, stream>>>(table);
    fill_table_k<<<EE / 256, 256, 0, stream>>>(ei, table);
    build_rev_k<<<EE / 256, 256, 0, stream>>>(ei, table, rev);
    init_csr_k<<<NN / 256, 256, 0, stream>>>(adj, wadj, cnt);
    fill_csr_k<<<EE / 256, 256, 0, stream>>>(ei, rev, pos, adj, wadj, cnt);
    hipMemsetAsync(zero, 0, 2048, stream);

    // bf16 weight copies (both layers at once)
    conv_k<<<1572864 / 2048, 256, 0, stream>>>(inw, inwb);
    conv_k<<<524288 / 2048, 256, 0, stream>>>(ow, owb);
    conv_k<<<524288 / 2048, 256, 0, stream>>>(etw, etwb);
    conv_k<<<1048576 / 2048, 256, 0, stream>>>(unw, unwb);
    conv_k<<<2097152 / 2048, 256, 0, stream>>>(uew, uewb);
    // bf16 activations for layer 0
    conv_k<<<1048576 / 2048, 256, 0, stream>>>(x, nfb);
    conv_k<<<16777216 / 2048, 256, 0, stream>>>(efin, efbA);

    for (int l = 0; l < 2; ++l) {
        const u16* efb_cur = l ? efbB : efbA;
        const u16* inwb_l = inwb + (size_t)l * 786432;
        const u16* owb_l  = owb  + (size_t)l * 262144;
        const u16* etwb_l = etwb + (size_t)l * 262144;
        const u16* unwb_l = unwb + (size_t)l * 524288;
        const u16* uewb_l = uewb + (size_t)l * 1048576;
        const float* inb_l  = inb  + (size_t)l * 1536;
        const float* ob_l   = ob   + (size_t)l * 512;
        const float* etb_l  = etb  + (size_t)l * 512;
        const float* etg_l  = etg  + (size_t)l * 512;
        const float* etbb_l = etbb + (size_t)l * 512;
        const float* unb_l  = unb  + (size_t)l * 512;
        const float* ueb_l  = ueb  + (size_t)l * 512;

        // qkv = nf @ inw^T + inb   (f32 out for attention)
        mgemm_k<0, 0, 1, 0, 12><<<192, 256, 0, stream>>>(
            nfb, inwb_l, inb_l, qkv, nullptr, NN, 3 * DND, DND,
            nullptr, nullptr, nullptr, nullptr, nullptr, nullptr, nullptr, nullptr, nullptr, nullptr);

        // sparse masked MHSA -> ctx (bf16)
        attn_sp_k<<<dim3(NN, 2), 256, 0, stream>>>(qkv, adj, wadj, cnt, ctxb);

        // x_upd = ctx @ ow^T + ob  (bf16 out, only consumed by update_node gather)
        mgemm_k<0, 0, 0, 1, 4><<<64, 256, 0, stream>>>(
            ctxb, owb_l, ob_l, nullptr, xupdb, NN, DND, DND,
            nullptr, nullptr, nullptr, nullptr, nullptr, nullptr, nullptr, nullptr, nullptr, nullptr);

        // scatter-max accumulators (subj+obj are adjacent -> one memset)
        hipMemsetAsync(subj, 0, (size_t)2 * NN * DND * 4, stream);

        // te = relu(BN(ef @ etw^T + etb)) with fused atomicMax scatter (no C write)
        mgemm_k<0, 2, 0, 0, 4><<<1024, 256, 0, stream>>>(
            efb_cur, etwb_l, etb_l, nullptr, nullptr, EE, DND, DND,
            nullptr, nullptr, nullptr, srcv, dstv, nullptr, etg_l, etbb_l, subj, obj);

        // sumso = bf16(subj + obj)
        sumso_k<<<1048576 / 2048, 256, 0, stream>>>(subj, obj, sums);

        // ef_next = (relu?)([nf[src], ef, ef[rev], nf[dst]] @ uew^T + ueb)
        if (l == 0)
            mgemm_k<1, 1, 0, 1, 4><<<1024, 256, 0, stream>>>(
                nullptr, uewb_l, ueb_l, nullptr, efbB, EE, DND, 2048,
                nfb, efb_cur, zero, srcv, dstv, rev, nullptr, nullptr, nullptr, nullptr);
        else
            mgemm_k<1, 0, 1, 0, 4><<<1024, 256, 0, stream>>>(
                nullptr, uewb_l, ueb_l, out_ef, nullptr, EE, DND, 2048,
                nfb, efb_cur, zero, srcv, dstv, rev, nullptr, nullptr, nullptr, nullptr);

        // nf_next = (relu?)([x_upd, subj+obj] @ unw^T + unb)
        if (l == 0)
            mgemm_k<2, 1, 0, 1, 4><<<64, 256, 0, stream>>>(
                nullptr, unwb_l, unb_l, nullptr, nfb, NN, DND, 1024,
                xupdb, sums, nullptr, nullptr, nullptr, nullptr, nullptr, nullptr, nullptr, nullptr);
        else
            mgemm_k<2, 0, 1, 0, 4><<<64, 256, 0, stream>>>(
                nullptr, unwb_l, unb_l, out_nf, nullptr, NN, DND, 1024,
                xupdb, sums, nullptr, nullptr, nullptr, nullptr, nullptr, nullptr, nullptr, nullptr);
    }
}

// Round 7
// 604.071 us; speedup vs baseline: 7.3706x; 1.3341x over previous
//
#include <hip/hip_runtime.h>
#include <hip/hip_bf16.h>

#define NN 2048
#define EE 32768
#define DND 512
#define NH 8
#define HD 64
#define MAXD 128
#define NEGF (-1e30f)
#define BN_SCALE 0.9999950000374997f  // 1/sqrt(1+1e-5)

typedef __attribute__((ext_vector_type(8))) short bf16x8;
typedef __attribute__((ext_vector_type(4))) float f32x4;
typedef unsigned short u16;
typedef unsigned int u32;

static __device__ __forceinline__ float4 ld4(const float* p) {
    return *reinterpret_cast<const float4*>(p);
}
static __device__ __forceinline__ u16 f2b(float f) {
    __hip_bfloat16 h = __float2bfloat16(f);
    return *reinterpret_cast<u16*>(&h);
}
static __device__ __forceinline__ void gl_lds(const u16* g, u16* l) {
    __builtin_amdgcn_global_load_lds((const __attribute__((address_space(1))) void*)g,
                                     (__attribute__((address_space(3))) void*)l, 16, 0, 0);
}

// ---------------- setup kernels ----------------

__global__ __launch_bounds__(256) void init_table_k(int* __restrict__ t) {
    int i = blockIdx.x * 256 + threadIdx.x;
    t[i] = -1;
}

__global__ __launch_bounds__(256) void fill_table_k(const int* __restrict__ ei, int* __restrict__ t) {
    int e = blockIdx.x * 256 + threadIdx.x;
    if (e < EE) t[(size_t)ei[e] * NN + ei[EE + e]] = e;
}

__global__ __launch_bounds__(256) void build_rev_k(const int* __restrict__ ei, const int* __restrict__ t,
                                                   int* __restrict__ rev) {
    int e = blockIdx.x * 256 + threadIdx.x;
    if (e < EE) rev[e] = t[(size_t)ei[EE + e] * NN + ei[e]];
}

// CSR: slot 0 = self (weight 1.0), then neighbors
__global__ __launch_bounds__(256) void init_csr_k(int* __restrict__ adj, float* __restrict__ wadj,
                                                  int* __restrict__ cnt) {
    int i = blockIdx.x * 256 + threadIdx.x;
    if (i < NN) { cnt[i] = 1; adj[i * MAXD] = i; wadj[i * MAXD] = 1.0f; }
}

__global__ __launch_bounds__(256) void fill_csr_k(const int* __restrict__ ei, const int* __restrict__ rev,
                                                  const float* __restrict__ pos,
                                                  int* __restrict__ adj, float* __restrict__ wadj,
                                                  int* __restrict__ cnt) {
    int e = blockIdx.x * 256 + threadIdx.x;
    if (e >= EE) return;
    int s = ei[e], d = ei[EE + e];
    float dx = pos[s * 3 + 0] - pos[d * 3 + 0];
    float dy = pos[s * 3 + 1] - pos[d * 3 + 1];
    float dz = pos[s * 3 + 2] - pos[d * 3 + 2];
    float w = 1.0f / (sqrtf(dx * dx + dy * dy + dz * dz) + 1e-6f);
    int slot = atomicAdd(&cnt[s], 1);
    if (slot < MAXD) { adj[s * MAXD + slot] = d; wadj[s * MAXD + slot] = w; }
    if (rev[e] < 0) {  // symmetric pair not otherwise present -> add mirror
        slot = atomicAdd(&cnt[d], 1);
        if (slot < MAXD) { adj[d * MAXD + slot] = s; wadj[d * MAXD + slot] = w; }
    }
}

// ---------------- f32 -> bf16 conversion (8 elems/thread) ----------------
__global__ __launch_bounds__(256) void conv_k(const float* __restrict__ src, u16* __restrict__ dst) {
    int i = (blockIdx.x * 256 + threadIdx.x) * 8;
    float4 a = ld4(src + i), b = ld4(src + i + 4);
    u16 o[8];
    o[0] = f2b(a.x); o[1] = f2b(a.y); o[2] = f2b(a.z); o[3] = f2b(a.w);
    o[4] = f2b(b.x); o[5] = f2b(b.y); o[6] = f2b(b.z); o[7] = f2b(b.w);
    *reinterpret_cast<int4*>(dst + i) = *reinterpret_cast<const int4*>(o);
}

// sumso = bf16(subj + obj)
__global__ __launch_bounds__(256) void sumso_k(const float* __restrict__ s, const float* __restrict__ o,
                                               u16* __restrict__ dst) {
    int i = (blockIdx.x * 256 + threadIdx.x) * 8;
    float4 a = ld4(s + i), b = ld4(o + i), c = ld4(s + i + 4), d = ld4(o + i + 4);
    u16 ov[8];
    ov[0] = f2b(a.x + b.x); ov[1] = f2b(a.y + b.y); ov[2] = f2b(a.z + b.z); ov[3] = f2b(a.w + b.w);
    ov[4] = f2b(c.x + d.x); ov[5] = f2b(c.y + d.y); ov[6] = f2b(c.z + d.z); ov[7] = f2b(c.w + d.w);
    *reinterpret_cast<int4*>(dst + i) = *reinterpret_cast<const int4*>(ov);
}

// ---------------- MFMA GEMM: C[M,Nc] = epi(Agather[M,K](bf16) @ B[Nc,K](bf16)^T + bias) ----
// All staged operands live inside d_ws; passed as u32 u16-element offsets from WS.
// MODE 0: A plain row-major (offset a_off), row length K
// MODE 1: A = [g0[src], g1, g1[rev]|zero, g0[dst]]   (K = 2048, 512-per-segment rows)
// MODE 2: A = [g0, g1]                               (K = 1024)
// EPI 0: +bias   EPI 1: relu(+bias)   EPI 2: relu((+bias)*BN_SCALE*eg+eb) + atomicMax scatter
// Staging (the R7 fix): BK=64 -> each row contributes 128 contiguous bytes per tile;
// 8 lanes cover one row, so every global_load_lds reads 8 FULL 128B lines (wave-
// coalesced) instead of 64 sparse 16B slivers -> 8x fewer L2/L3 requests.
// LDS tile: [row 0..127][8 chunks of 16B], chunk position XOR-swizzled by (row&7)
// on BOTH the global source (per-lane addr) and the ds_read (bank-conflict-free).
// 2-deep double buffer, counted vmcnt(8), raw s_barrier.
template <int MODE, int EPI, int WF32, int WBF16, int GY>
__global__ __launch_bounds__(256) void mgemm_k(
    const u16* __restrict__ WS, u32 a_off, u32 b_off, const float* __restrict__ bias,
    float* __restrict__ Cf, u16* __restrict__ Cb, int M, int Nc, int K,
    u32 g0_off, u32 g1_off, u32 gz_off,
    const int* __restrict__ srcv, const int* __restrict__ dstv, const int* __restrict__ revv,
    const float* __restrict__ eg, const float* __restrict__ eb,
    float* __restrict__ subj, float* __restrict__ obj)
{
    __shared__ u16 As2[2][8192];
    __shared__ u16 Bs2[2][8192];
    const int tid = threadIdx.x, lane = tid & 63, w = tid >> 6;
    const int wr = w >> 1, wc = w & 1;
    // grid swizzle: b = (xcd, kb); col = kb % GY (fast), rowblk = (kb / GY)*8 + xcd
    const int b = blockIdx.x;
    const int xcd = b & 7, kb = b >> 3;
    const int bm = ((kb / GY) * 8 + xcd) * 128;
    const int bn = (kb % GY) * 128;

    const int rl = lane >> 3;                      // sub-row 0..7 within 8-row group
    const u32 lx = (u32)(((lane & 7) ^ rl) * 8);   // swizzled 16B-chunk offset (u16 units)

    // hoisted per-lane row offsets (u16 elements from WS) per q-group
    u32 offA0[4], offA1[4], offA2[4], offA3[4], offB[4];
#pragma unroll
    for (int q = 0; q < 4; ++q) {
        const int ra = bm + w * 32 + q * 8 + rl;
        if (MODE == 0) {
            offA0[q] = a_off + (u32)ra * (u32)K + lx;
        } else if (MODE == 1) {
            offA0[q] = g0_off + (u32)srcv[ra] * 512u + lx;
            offA1[q] = g1_off + (u32)ra * 512u + lx;
            const int rv = revv[ra];
            offA2[q] = (rv >= 0 ? g1_off + (u32)rv * 512u : gz_off) + lx;
            offA3[q] = g0_off + (u32)dstv[ra] * 512u + lx;
        } else {
            offA0[q] = g0_off + (u32)ra * 512u + lx;
            offA1[q] = g1_off + (u32)ra * 512u + lx;
        }
        offB[q] = b_off + (u32)(bn + w * 32 + q * 8 + rl) * (u32)K + lx;
    }

    const int nks = K >> 6;  // BK = 64
    const int kq = lane >> 4, li = lane & 15;

    auto stage = [&](int t, int buf) {
        const u32 k0 = (u32)t * 64u;
        const int seg = (MODE == 0) ? 0 : (int)(k0 >> 9);
#pragma unroll
        for (int q = 0; q < 4; ++q) {
            u32 oa;
            if (MODE == 0)      oa = offA0[q];
            else if (MODE == 1) oa = (seg == 0 ? offA0[q] : seg == 1 ? offA1[q] : seg == 2 ? offA2[q] : offA3[q]);
            else                oa = (seg == 0 ? offA0[q] : offA1[q]);
            const u32 koff = (MODE == 0) ? k0 : (k0 & 511u);
            gl_lds(WS + oa + koff, &As2[buf][(w * 32 + q * 8) * 64]);
        }
#pragma unroll
        for (int q = 0; q < 4; ++q)
            gl_lds(WS + offB[q] + k0, &Bs2[buf][(w * 32 + q * 8) * 64]);
    };

    f32x4 acc[4][4] = {};
    const int baseA = (wr * 64 + li) * 64 + ((kq ^ (li & 7)) * 8);
    const int baseB = (wc * 64 + li) * 64 + ((kq ^ (li & 7)) * 8);

    stage(0, 0);
    for (int t = 0; t < nks; ++t) {
        const int cur = t & 1;
        if (t + 1 < nks) stage(t + 1, cur ^ 1);
        if (t + 1 < nks) asm volatile("s_waitcnt vmcnt(8)" ::: "memory");
        else             asm volatile("s_waitcnt vmcnt(0)" ::: "memory");
        __builtin_amdgcn_s_barrier();
        __builtin_amdgcn_sched_barrier(0);
#pragma unroll
        for (int sub = 0; sub < 2; ++sub) {
            const int sx = sub << 5;  // flip chunk bit2 (64B) in u16 units
            bf16x8 af[4], bf[4];
#pragma unroll
            for (int m = 0; m < 4; ++m)
                af[m] = *reinterpret_cast<const bf16x8*>(&As2[cur][(baseA + m * 1024) ^ sx]);
#pragma unroll
            for (int n = 0; n < 4; ++n)
                bf[n] = *reinterpret_cast<const bf16x8*>(&Bs2[cur][(baseB + n * 1024) ^ sx]);
#pragma unroll
            for (int m = 0; m < 4; ++m)
#pragma unroll
                for (int n = 0; n < 4; ++n)
                    acc[m][n] = __builtin_amdgcn_mfma_f32_16x16x32_bf16(af[m], bf[n], acc[m][n], 0, 0, 0);
        }
        __builtin_amdgcn_s_barrier();
        __builtin_amdgcn_sched_barrier(0);
    }

    // epilogue: C[row=(lane>>4)*4+i][col=lane&15] per 16x16 fragment
    float bsv[4], scv[4], shv[4];
#pragma unroll
    for (int n = 0; n < 4; ++n) {
        const int col = bn + wc * 64 + n * 16 + li;
        bsv[n] = bias[col];
        if (EPI == 2) { scv[n] = BN_SCALE * eg[col]; shv[n] = eb[col]; }
    }
#pragma unroll
    for (int m = 0; m < 4; ++m) {
        int se[4], de[4];
        if (EPI == 2) {
#pragma unroll
            for (int i = 0; i < 4; ++i) {
                const int r = bm + wr * 64 + m * 16 + (lane >> 4) * 4 + i;
                se[i] = srcv[r]; de[i] = dstv[r];
            }
        }
#pragma unroll
        for (int n = 0; n < 4; ++n) {
            const int col = bn + wc * 64 + n * 16 + li;
#pragma unroll
            for (int i = 0; i < 4; ++i) {
                float v = acc[m][n][i] + bsv[n];
                if (EPI == 2) {
                    v = fmaxf(fmaf(v, scv[n], shv[n]), 0.f);
                    const unsigned uv = __float_as_uint(v);
                    atomicMax(reinterpret_cast<unsigned*>(subj) + (size_t)se[i] * DND + col, uv);
                    atomicMax(reinterpret_cast<unsigned*>(obj) + (size_t)de[i] * DND + col, uv);
                } else {
                    if (EPI == 1) v = fmaxf(v, 0.f);
                    const int r = bm + wr * 64 + m * 16 + (lane >> 4) * 4 + i;
                    if (WF32) Cf[(size_t)r * Nc + col] = v;
                    if (WBF16) Cb[(size_t)r * Nc + col] = f2b(v);
                }
            }
        }
    }
}

// ---------------- sparse attention: 1 wave per (node, head) ----------------
__global__ __launch_bounds__(256) void attn_sp_k(const float* __restrict__ qkv,
                                                 const int* __restrict__ adj,
                                                 const float* __restrict__ wadj,
                                                 const int* __restrict__ cnt,
                                                 u16* __restrict__ ctxb)
{
    const int i = blockIdx.x;
    const int wv = threadIdx.x >> 6, lane = threadIdx.x & 63;
    const int h = blockIdx.y * 4 + wv;
    __shared__ float qs[4][64];
    qs[wv][lane] = qkv[(size_t)i * 1536 + h * HD + lane] * 0.125f;  // 1/sqrt(64)
    __syncthreads();
    int deg = cnt[i];
    if (deg > MAXD) deg = MAXD;
    float m = -3.0e38f, lsum = 0.f, c = 0.f;
    for (int base = 0; base < deg; base += 64) {
        int nn_ = deg - base; if (nn_ > 64) nn_ = 64;
        int j = 0;
        float s = NEGF;
        if (lane < nn_) {
            j = adj[i * MAXD + base + lane];
            const float wgt = wadj[i * MAXD + base + lane];
            const float* kr = qkv + (size_t)j * 1536 + DND + h * HD;
            float accd = 0.f;
#pragma unroll
            for (int d4 = 0; d4 < 16; ++d4) {
                float4 kv = ld4(kr + d4 * 4);
                accd = fmaf(qs[wv][d4 * 4 + 0], kv.x, accd);
                accd = fmaf(qs[wv][d4 * 4 + 1], kv.y, accd);
                accd = fmaf(qs[wv][d4 * 4 + 2], kv.z, accd);
                accd = fmaf(qs[wv][d4 * 4 + 3], kv.w, accd);
            }
            s = accd + wgt;
        }
        float mloc = s;
#pragma unroll
        for (int o = 1; o < 64; o <<= 1) mloc = fmaxf(mloc, __shfl_xor(mloc, o, 64));
        const float mnew = fmaxf(m, mloc);
        const float alpha = __expf(m - mnew);
        const float p = (lane < nn_) ? __expf(s - mnew) : 0.f;
        float ps = p;
#pragma unroll
        for (int o = 1; o < 64; o <<= 1) ps += __shfl_xor(ps, o, 64);
        lsum = lsum * alpha + ps;
        c *= alpha;
        for (int l = 0; l < nn_; ++l) {
            const float pj = __shfl(p, l, 64);
            const int jj = __shfl(j, l, 64);
            c = fmaf(pj, qkv[(size_t)jj * 1536 + 2 * DND + h * HD + lane], c);
        }
        m = mnew;
    }
    ctxb[(size_t)i * DND + h * HD + lane] = f2b(c / lsum);
}

// ---------------- host orchestration ----------------
extern "C" void kernel_launch(void* const* d_in, const int* in_sizes, int n_in,
                              void* d_out, int out_size, void* d_ws, size_t ws_size,
                              hipStream_t stream)
{
    const float* x    = (const float*)d_in[0];
    const float* efin = (const float*)d_in[1];
    const float* pos  = (const float*)d_in[2];
    const float* inw  = (const float*)d_in[3];
    const float* inb  = (const float*)d_in[4];
    const float* ow   = (const float*)d_in[5];
    const float* ob   = (const float*)d_in[6];
    const float* etw  = (const float*)d_in[7];
    const float* etb  = (const float*)d_in[8];
    const float* etg  = (const float*)d_in[9];
    const float* etbb = (const float*)d_in[10];
    const float* unw  = (const float*)d_in[11];
    const float* unb  = (const float*)d_in[12];
    const float* uew  = (const float*)d_in[13];
    const float* ueb  = (const float*)d_in[14];
    const int*   ei   = (const int*)d_in[15];

    // workspace layout (offsets in floats)
    float* W = (float*)d_ws;
    float* qkv   = W;                                //          0 .. 3,145,728  (NN*3*DND)
    float* subj  = W + 3145728;                      //  3,145,728 .. 4,194,304  (NN*DND)
    float* obj   = W + 4194304;                      //  4,194,304 .. 5,242,880  (NN*DND)
    int*   rev   = (int*)(W + 5242880);              //  .. 5,275,648  (EE ints)
    u16*   zero  = (u16*)(W + 5275648);              //  .. 5,276,160  (1024 u16)
    int*   adj   = (int*)(W + 5276160);              //  .. 5,538,304  (NN*MAXD ints)
    float* wadj  = W + 5538304;                      //  .. 5,800,448  (NN*MAXD)
    int*   cnt   = (int*)(W + 5800448);              //  .. 5,802,496  (NN ints)
    u16*   ctxb  = (u16*)(W + 5802496);              //  .. 6,326,784  (NN*DND u16)
    u16*   xupdb = (u16*)(W + 6326784);              //  .. 6,851,072  (NN*DND u16)
    u16*   sums  = (u16*)(W + 6851072);              //  .. 7,375,360  (NN*DND u16)
    u16*   nfb   = (u16*)(W + 7375360);              //  .. 7,899,648  (NN*DND u16)
    u16*   wbf   = (u16*)(W + 7899648);              //  .. 10,783,232 (5,767,168 u16)
    u16*   efbA  = (u16*)(W + 10783232);             //  .. 19,171,840 (EE*DND u16)
    u16*   efbB  = (u16*)(W + 19171840);             //  .. 27,560,448 (EE*DND u16)
    int*   table = (int*)efbA;                       //  alias: setup-only (16 MB < 32 MB)
    // total: 27,560,448 floats = 110.2 MB

    u16* inwb = wbf;
    u16* owb  = wbf + 1572864;
    u16* etwb = wbf + 2097152;
    u16* unwb = wbf + 2621440;
    u16* uewb = wbf + 3670016;

    float* out_nf = (float*)d_out;
    float* out_ef = out_nf + (size_t)NN * DND;

    const int* srcv = ei;
    const int* dstv = ei + EE;

    const u16* WSu = (const u16*)d_ws;
    auto uoff = [&](const void* p) { return (u32)((const u16*)p - WSu); };

    // setup: edge table, reverse-edge index, sparse-attention CSR (table aliases efbA; before conv)
    init_table_k<<<NN * NN / 256, 256, 0, stream>>>(table);
    fill_table_k<<<EE / 256, 256, 0, stream>>>(ei, table);
    build_rev_k<<<EE / 256, 256, 0, stream>>>(ei, table, rev);
    init_csr_k<<<NN / 256, 256, 0, stream>>>(adj, wadj, cnt);
    fill_csr_k<<<EE / 256, 256, 0, stream>>>(ei, rev, pos, adj, wadj, cnt);
    hipMemsetAsync(zero, 0, 2048, stream);

    // bf16 weight copies (both layers at once)
    conv_k<<<1572864 / 2048, 256, 0, stream>>>(inw, inwb);
    conv_k<<<524288 / 2048, 256, 0, stream>>>(ow, owb);
    conv_k<<<524288 / 2048, 256, 0, stream>>>(etw, etwb);
    conv_k<<<1048576 / 2048, 256, 0, stream>>>(unw, unwb);
    conv_k<<<2097152 / 2048, 256, 0, stream>>>(uew, uewb);
    // bf16 activations for layer 0
    conv_k<<<1048576 / 2048, 256, 0, stream>>>(x, nfb);
    conv_k<<<16777216 / 2048, 256, 0, stream>>>(efin, efbA);

    for (int l = 0; l < 2; ++l) {
        const u16* efb_cur = l ? efbB : efbA;
        const u16* inwb_l = inwb + (size_t)l * 786432;
        const u16* owb_l  = owb  + (size_t)l * 262144;
        const u16* etwb_l = etwb + (size_t)l * 262144;
        const u16* unwb_l = unwb + (size_t)l * 524288;
        const u16* uewb_l = uewb + (size_t)l * 1048576;
        const float* inb_l  = inb  + (size_t)l * 1536;
        const float* ob_l   = ob   + (size_t)l * 512;
        const float* etb_l  = etb  + (size_t)l * 512;
        const float* etg_l  = etg  + (size_t)l * 512;
        const float* etbb_l = etbb + (size_t)l * 512;
        const float* unb_l  = unb  + (size_t)l * 512;
        const float* ueb_l  = ueb  + (size_t)l * 512;

        // qkv = nf @ inw^T + inb   (f32 out for attention)
        mgemm_k<0, 0, 1, 0, 12><<<192, 256, 0, stream>>>(
            WSu, uoff(nfb), uoff(inwb_l), inb_l, qkv, nullptr, NN, 3 * DND, DND,
            0, 0, 0, nullptr, nullptr, nullptr, nullptr, nullptr, nullptr, nullptr);

        // sparse masked MHSA -> ctx (bf16)
        attn_sp_k<<<dim3(NN, 2), 256, 0, stream>>>(qkv, adj, wadj, cnt, ctxb);

        // x_upd = ctx @ ow^T + ob  (bf16 out, only consumed by update_node gather)
        mgemm_k<0, 0, 0, 1, 4><<<64, 256, 0, stream>>>(
            WSu, uoff(ctxb), uoff(owb_l), ob_l, nullptr, xupdb, NN, DND, DND,
            0, 0, 0, nullptr, nullptr, nullptr, nullptr, nullptr, nullptr, nullptr);

        // scatter-max accumulators (subj+obj are adjacent -> one memset)
        hipMemsetAsync(subj, 0, (size_t)2 * NN * DND * 4, stream);

        // te = relu(BN(ef @ etw^T + etb)) with fused atomicMax scatter (no C write)
        mgemm_k<0, 2, 0, 0, 4><<<1024, 256, 0, stream>>>(
            WSu, uoff(efb_cur), uoff(etwb_l), etb_l, nullptr, nullptr, EE, DND, DND,
            0, 0, 0, srcv, dstv, nullptr, etg_l, etbb_l, subj, obj);

        // sumso = bf16(subj + obj)
        sumso_k<<<1048576 / 2048, 256, 0, stream>>>(subj, obj, sums);

        // ef_next = (relu?)([nf[src], ef, ef[rev], nf[dst]] @ uew^T + ueb)
        if (l == 0)
            mgemm_k<1, 1, 0, 1, 4><<<1024, 256, 0, stream>>>(
                WSu, 0, uoff(uewb_l), ueb_l, nullptr, efbB, EE, DND, 2048,
                uoff(nfb), uoff(efb_cur), uoff(zero), srcv, dstv, rev, nullptr, nullptr, nullptr, nullptr);
        else
            mgemm_k<1, 0, 1, 0, 4><<<1024, 256, 0, stream>>>(
                WSu, 0, uoff(uewb_l), ueb_l, out_ef, nullptr, EE, DND, 2048,
                uoff(nfb), uoff(efb_cur), uoff(zero), srcv, dstv, rev, nullptr, nullptr, nullptr, nullptr);

        // nf_next = (relu?)([x_upd, subj+obj] @ unw^T + unb)
        if (l == 0)
            mgemm_k<2, 1, 0, 1, 4><<<64, 256, 0, stream>>>(
                WSu, 0, uoff(unwb_l), unb_l, nullptr, nfb, NN, DND, 1024,
                uoff(xupdb), uoff(sums), 0, nullptr, nullptr, nullptr, nullptr, nullptr, nullptr, nullptr);
        else
            mgemm_k<2, 0, 1, 0, 4><<<64, 256, 0, stream>>>(
                WSu, 0, uoff(unwb_l), unb_l, out_nf, nullptr, NN, DND, 1024,
                uoff(xupdb), uoff(sums), 0, nullptr, nullptr, nullptr, nullptr, nullptr, nullptr, nullptr);
    }
}

// Round 8
// 509.914 us; speedup vs baseline: 8.7316x; 1.1847x over previous
//
#include <hip/hip_runtime.h>
#include <hip/hip_bf16.h>

#define NN 2048
#define EE 32768
#define DND 512
#define NH 8
#define HD 64
#define MAXD 128
#define NEGF (-1e30f)
#define BN_SCALE 0.9999950000374997f  // 1/sqrt(1+1e-5)

typedef __attribute__((ext_vector_type(8))) short bf16x8;
typedef __attribute__((ext_vector_type(4))) float f32x4;
typedef unsigned short u16;
typedef unsigned int u32;

static __device__ __forceinline__ float4 ld4(const float* p) {
    return *reinterpret_cast<const float4*>(p);
}
static __device__ __forceinline__ u16 f2b(float f) {
    __hip_bfloat16 h = __float2bfloat16(f);
    return *reinterpret_cast<u16*>(&h);
}
static __device__ __forceinline__ float b2f(u32 bits) {
    return __uint_as_float(bits << 16);
}
static __device__ __forceinline__ void gl_lds(const u16* g, u16* l) {
    __builtin_amdgcn_global_load_lds((const __attribute__((address_space(1))) void*)g,
                                     (__attribute__((address_space(3))) void*)l, 16, 0, 0);
}

// ---------------- setup kernels ----------------

__global__ __launch_bounds__(256) void init_table_k(int* __restrict__ t) {
    int i = blockIdx.x * 256 + threadIdx.x;
    t[i] = -1;
}

__global__ __launch_bounds__(256) void fill_table_k(const int* __restrict__ ei, int* __restrict__ t) {
    int e = blockIdx.x * 256 + threadIdx.x;
    if (e < EE) t[(size_t)ei[e] * NN + ei[EE + e]] = e;
}

__global__ __launch_bounds__(256) void build_rev_k(const int* __restrict__ ei, const int* __restrict__ t,
                                                   int* __restrict__ rev) {
    int e = blockIdx.x * 256 + threadIdx.x;
    if (e < EE) rev[e] = t[(size_t)ei[EE + e] * NN + ei[e]];
}

// attention CSR: slot 0 = self (weight 1.0), then neighbors
__global__ __launch_bounds__(256) void init_csr_k(int* __restrict__ adj, float* __restrict__ wadj,
                                                  int* __restrict__ cnt) {
    int i = blockIdx.x * 256 + threadIdx.x;
    if (i < NN) { cnt[i] = 1; adj[i * MAXD] = i; wadj[i * MAXD] = 1.0f; }
}

__global__ __launch_bounds__(256) void fill_csr_k(const int* __restrict__ ei, const int* __restrict__ rev,
                                                  const float* __restrict__ pos,
                                                  int* __restrict__ adj, float* __restrict__ wadj,
                                                  int* __restrict__ cnt) {
    int e = blockIdx.x * 256 + threadIdx.x;
    if (e >= EE) return;
    int s = ei[e], d = ei[EE + e];
    float dx = pos[s * 3 + 0] - pos[d * 3 + 0];
    float dy = pos[s * 3 + 1] - pos[d * 3 + 1];
    float dz = pos[s * 3 + 2] - pos[d * 3 + 2];
    float w = 1.0f / (sqrtf(dx * dx + dy * dy + dz * dz) + 1e-6f);
    int slot = atomicAdd(&cnt[s], 1);
    if (slot < MAXD) { adj[s * MAXD + slot] = d; wadj[s * MAXD + slot] = w; }
    if (rev[e] < 0) {  // symmetric pair not otherwise present -> add mirror
        slot = atomicAdd(&cnt[d], 1);
        if (slot < MAXD) { adj[d * MAXD + slot] = s; wadj[d * MAXD + slot] = w; }
    }
}

// out/in edge-id CSRs for the scatter-max gather
__global__ __launch_bounds__(256) void init_ecsr_k(int* __restrict__ ocnt, int* __restrict__ icnt) {
    int i = blockIdx.x * 256 + threadIdx.x;
    if (i < NN) { ocnt[i] = 0; icnt[i] = 0; }
}

__global__ __launch_bounds__(256) void fill_ecsr_k(const int* __restrict__ ei,
                                                   int* __restrict__ oadj, int* __restrict__ ocnt,
                                                   int* __restrict__ iadj, int* __restrict__ icnt) {
    int e = blockIdx.x * 256 + threadIdx.x;
    if (e >= EE) return;
    int s = ei[e], d = ei[EE + e];
    int slot = atomicAdd(&ocnt[s], 1);
    if (slot < MAXD) oadj[s * MAXD + slot] = e;
    slot = atomicAdd(&icnt[d], 1);
    if (slot < MAXD) iadj[d * MAXD + slot] = e;
}

// ---------------- f32 -> bf16 conversion (8 elems/thread) ----------------
__global__ __launch_bounds__(256) void conv_k(const float* __restrict__ src, u16* __restrict__ dst) {
    int i = (blockIdx.x * 256 + threadIdx.x) * 8;
    float4 a = ld4(src + i), b = ld4(src + i + 4);
    u16 o[8];
    o[0] = f2b(a.x); o[1] = f2b(a.y); o[2] = f2b(a.z); o[3] = f2b(a.w);
    o[4] = f2b(b.x); o[5] = f2b(b.y); o[6] = f2b(b.z); o[7] = f2b(b.w);
    *reinterpret_cast<int4*>(dst + i) = *reinterpret_cast<const int4*>(o);
}

// ---------------- gather-max: sums[i] = bf16(max_out te[e] + max_in te[e]) ----------------
// One block per node; thread c2 handles cols 2*c2, 2*c2+1 (u32 = 2 bf16).
// te >= 0 (post-ReLU), so init 0 == reference's -inf -> 0 empty-segment convention.
__global__ __launch_bounds__(256) void gather_max_k(const u16* __restrict__ te,
                                                    const int* __restrict__ oadj, const int* __restrict__ ocnt,
                                                    const int* __restrict__ iadj, const int* __restrict__ icnt,
                                                    u16* __restrict__ sums)
{
    const int i = blockIdx.x;
    const int c2 = threadIdx.x;  // 0..255
    float ms0 = 0.f, ms1 = 0.f, mo0 = 0.f, mo1 = 0.f;
    int no = ocnt[i]; if (no > MAXD) no = MAXD;
    for (int s = 0; s < no; ++s) {
        const int e = oadj[i * MAXD + s];
        const u32 v = *reinterpret_cast<const u32*>(te + (size_t)e * DND + c2 * 2);
        ms0 = fmaxf(ms0, b2f(v & 0xffffu));
        ms1 = fmaxf(ms1, b2f(v >> 16));
    }
    int ni = icnt[i]; if (ni > MAXD) ni = MAXD;
    for (int s = 0; s < ni; ++s) {
        const int e = iadj[i * MAXD + s];
        const u32 v = *reinterpret_cast<const u32*>(te + (size_t)e * DND + c2 * 2);
        mo0 = fmaxf(mo0, b2f(v & 0xffffu));
        mo1 = fmaxf(mo1, b2f(v >> 16));
    }
    const u32 r = (u32)f2b(ms0 + mo0) | ((u32)f2b(ms1 + mo1) << 16);
    *reinterpret_cast<u32*>(sums + (size_t)i * DND + c2 * 2) = r;
}

// ---------------- MFMA GEMM: C[M,Nc] = epi(Agather[M,K](bf16) @ B[Nc,K](bf16)^T + bias) ----
// All staged operands live inside d_ws; passed as u32 u16-element offsets from WS.
// MODE 0: A plain row-major (offset a_off), row length K
// MODE 1: A = [g0[src], g1, g1[rev]|zero, g0[dst]]   (K = 2048, 512-per-segment rows)
// MODE 2: A = [g0, g1]                               (K = 1024)
// EPI 0: +bias   EPI 1: relu(+bias)   EPI 2: relu((+bias)*BN_SCALE*eg+eb)
// Staging: BK=64 -> 8 lanes cover one row's 128B; every global_load_lds reads 8
// FULL 128B lines (wave-coalesced). LDS tile [row][8 x 16B chunks], chunk index
// XOR-swizzled by row&7 on BOTH global source and ds_read (bank-conflict-free).
// 2-deep double buffer, counted vmcnt(8), raw s_barrier.
template <int MODE, int EPI, int WF32, int WBF16, int GY>
__global__ __launch_bounds__(256) void mgemm_k(
    const u16* __restrict__ WS, u32 a_off, u32 b_off, const float* __restrict__ bias,
    float* __restrict__ Cf, u16* __restrict__ Cb, int M, int Nc, int K,
    u32 g0_off, u32 g1_off, u32 gz_off,
    const int* __restrict__ srcv, const int* __restrict__ dstv, const int* __restrict__ revv,
    const float* __restrict__ eg, const float* __restrict__ eb)
{
    __shared__ u16 As2[2][8192];
    __shared__ u16 Bs2[2][8192];
    const int tid = threadIdx.x, lane = tid & 63, w = tid >> 6;
    const int wr = w >> 1, wc = w & 1;
    // grid swizzle: b = (xcd, kb); col = kb % GY (fast), rowblk = (kb / GY)*8 + xcd
    const int b = blockIdx.x;
    const int xcd = b & 7, kb = b >> 3;
    const int bm = ((kb / GY) * 8 + xcd) * 128;
    const int bn = (kb % GY) * 128;

    const int rl = lane >> 3;                      // sub-row 0..7 within 8-row group
    const u32 lx = (u32)(((lane & 7) ^ rl) * 8);   // swizzled 16B-chunk offset (u16 units)

    u32 offA0[4], offA1[4], offA2[4], offA3[4], offB[4];
#pragma unroll
    for (int q = 0; q < 4; ++q) {
        const int ra = bm + w * 32 + q * 8 + rl;
        if (MODE == 0) {
            offA0[q] = a_off + (u32)ra * (u32)K + lx;
        } else if (MODE == 1) {
            offA0[q] = g0_off + (u32)srcv[ra] * 512u + lx;
            offA1[q] = g1_off + (u32)ra * 512u + lx;
            const int rv = revv[ra];
            offA2[q] = (rv >= 0 ? g1_off + (u32)rv * 512u : gz_off) + lx;
            offA3[q] = g0_off + (u32)dstv[ra] * 512u + lx;
        } else {
            offA0[q] = g0_off + (u32)ra * 512u + lx;
            offA1[q] = g1_off + (u32)ra * 512u + lx;
        }
        offB[q] = b_off + (u32)(bn + w * 32 + q * 8 + rl) * (u32)K + lx;
    }

    const int nks = K >> 6;  // BK = 64
    const int kq = lane >> 4, li = lane & 15;

    auto stage = [&](int t, int buf) {
        const u32 k0 = (u32)t * 64u;
        const int seg = (MODE == 0) ? 0 : (int)(k0 >> 9);
#pragma unroll
        for (int q = 0; q < 4; ++q) {
            u32 oa;
            if (MODE == 0)      oa = offA0[q];
            else if (MODE == 1) oa = (seg == 0 ? offA0[q] : seg == 1 ? offA1[q] : seg == 2 ? offA2[q] : offA3[q]);
            else                oa = (seg == 0 ? offA0[q] : offA1[q]);
            const u32 koff = (MODE == 0) ? k0 : (k0 & 511u);
            gl_lds(WS + oa + koff, &As2[buf][(w * 32 + q * 8) * 64]);
        }
#pragma unroll
        for (int q = 0; q < 4; ++q)
            gl_lds(WS + offB[q] + k0, &Bs2[buf][(w * 32 + q * 8) * 64]);
    };

    f32x4 acc[4][4] = {};
    const int baseA = (wr * 64 + li) * 64 + ((kq ^ (li & 7)) * 8);
    const int baseB = (wc * 64 + li) * 64 + ((kq ^ (li & 7)) * 8);

    stage(0, 0);
    for (int t = 0; t < nks; ++t) {
        const int cur = t & 1;
        if (t + 1 < nks) stage(t + 1, cur ^ 1);
        if (t + 1 < nks) asm volatile("s_waitcnt vmcnt(8)" ::: "memory");
        else             asm volatile("s_waitcnt vmcnt(0)" ::: "memory");
        __builtin_amdgcn_s_barrier();
        __builtin_amdgcn_sched_barrier(0);
#pragma unroll
        for (int sub = 0; sub < 2; ++sub) {
            const int sx = sub << 5;  // flip chunk bit2 (64B) in u16 units
            bf16x8 af[4], bf[4];
#pragma unroll
            for (int m = 0; m < 4; ++m)
                af[m] = *reinterpret_cast<const bf16x8*>(&As2[cur][(baseA + m * 1024) ^ sx]);
#pragma unroll
            for (int n = 0; n < 4; ++n)
                bf[n] = *reinterpret_cast<const bf16x8*>(&Bs2[cur][(baseB + n * 1024) ^ sx]);
#pragma unroll
            for (int m = 0; m < 4; ++m)
#pragma unroll
                for (int n = 0; n < 4; ++n)
                    acc[m][n] = __builtin_amdgcn_mfma_f32_16x16x32_bf16(af[m], bf[n], acc[m][n], 0, 0, 0);
        }
        __builtin_amdgcn_s_barrier();
        __builtin_amdgcn_sched_barrier(0);
    }

    // epilogue: C[row=(lane>>4)*4+i][col=lane&15] per 16x16 fragment
    float bsv[4], scv[4], shv[4];
#pragma unroll
    for (int n = 0; n < 4; ++n) {
        const int col = bn + wc * 64 + n * 16 + li;
        bsv[n] = bias[col];
        if (EPI == 2) { scv[n] = BN_SCALE * eg[col]; shv[n] = eb[col]; }
    }
#pragma unroll
    for (int m = 0; m < 4; ++m) {
#pragma unroll
        for (int n = 0; n < 4; ++n) {
            const int col = bn + wc * 64 + n * 16 + li;
#pragma unroll
            for (int i = 0; i < 4; ++i) {
                float v = acc[m][n][i] + bsv[n];
                if (EPI == 2) v = fmaxf(fmaf(v, scv[n], shv[n]), 0.f);
                else if (EPI == 1) v = fmaxf(v, 0.f);
                const int r = bm + wr * 64 + m * 16 + (lane >> 4) * 4 + i;
                if (WF32) Cf[(size_t)r * Nc + col] = v;
                if (WBF16) Cb[(size_t)r * Nc + col] = f2b(v);
            }
        }
    }
}

// ---------------- sparse attention: 1 wave per (node, head) ----------------
__global__ __launch_bounds__(256) void attn_sp_k(const float* __restrict__ qkv,
                                                 const int* __restrict__ adj,
                                                 const float* __restrict__ wadj,
                                                 const int* __restrict__ cnt,
                                                 u16* __restrict__ ctxb)
{
    const int i = blockIdx.x;
    const int wv = threadIdx.x >> 6, lane = threadIdx.x & 63;
    const int h = blockIdx.y * 4 + wv;
    __shared__ float qs[4][64];
    qs[wv][lane] = qkv[(size_t)i * 1536 + h * HD + lane] * 0.125f;  // 1/sqrt(64)
    __syncthreads();
    int deg = cnt[i];
    if (deg > MAXD) deg = MAXD;
    float m = -3.0e38f, lsum = 0.f, c = 0.f;
    for (int base = 0; base < deg; base += 64) {
        int nn_ = deg - base; if (nn_ > 64) nn_ = 64;
        int j = 0;
        float s = NEGF;
        if (lane < nn_) {
            j = adj[i * MAXD + base + lane];
            const float wgt = wadj[i * MAXD + base + lane];
            const float* kr = qkv + (size_t)j * 1536 + DND + h * HD;
            float accd = 0.f;
#pragma unroll
            for (int d4 = 0; d4 < 16; ++d4) {
                float4 kv = ld4(kr + d4 * 4);
                accd = fmaf(qs[wv][d4 * 4 + 0], kv.x, accd);
                accd = fmaf(qs[wv][d4 * 4 + 1], kv.y, accd);
                accd = fmaf(qs[wv][d4 * 4 + 2], kv.z, accd);
                accd = fmaf(qs[wv][d4 * 4 + 3], kv.w, accd);
            }
            s = accd + wgt;
        }
        float mloc = s;
#pragma unroll
        for (int o = 1; o < 64; o <<= 1) mloc = fmaxf(mloc, __shfl_xor(mloc, o, 64));
        const float mnew = fmaxf(m, mloc);
        const float alpha = __expf(m - mnew);
        const float p = (lane < nn_) ? __expf(s - mnew) : 0.f;
        float ps = p;
#pragma unroll
        for (int o = 1; o < 64; o <<= 1) ps += __shfl_xor(ps, o, 64);
        lsum = lsum * alpha + ps;
        c *= alpha;
        for (int l = 0; l < nn_; ++l) {
            const float pj = __shfl(p, l, 64);
            const int jj = __shfl(j, l, 64);
            c = fmaf(pj, qkv[(size_t)jj * 1536 + 2 * DND + h * HD + lane], c);
        }
        m = mnew;
    }
    ctxb[(size_t)i * DND + h * HD + lane] = f2b(c / lsum);
}

// ---------------- host orchestration ----------------
extern "C" void kernel_launch(void* const* d_in, const int* in_sizes, int n_in,
                              void* d_out, int out_size, void* d_ws, size_t ws_size,
                              hipStream_t stream)
{
    const float* x    = (const float*)d_in[0];
    const float* efin = (const float*)d_in[1];
    const float* pos  = (const float*)d_in[2];
    const float* inw  = (const float*)d_in[3];
    const float* inb  = (const float*)d_in[4];
    const float* ow   = (const float*)d_in[5];
    const float* ob   = (const float*)d_in[6];
    const float* etw  = (const float*)d_in[7];
    const float* etb  = (const float*)d_in[8];
    const float* etg  = (const float*)d_in[9];
    const float* etbb = (const float*)d_in[10];
    const float* unw  = (const float*)d_in[11];
    const float* unb  = (const float*)d_in[12];
    const float* uew  = (const float*)d_in[13];
    const float* ueb  = (const float*)d_in[14];
    const int*   ei   = (const int*)d_in[15];

    // workspace layout (offsets in floats)
    float* W = (float*)d_ws;
    float* qkv   = W;                                // union: qkv (3.15M) / te (8.39M)
    u16*   te    = (u16*)W;                          // te = EE*DND u16, dead-overlaps qkv
    int*   rev   = (int*)(W + 8388608);              //  .. 8,421,376  (EE ints)
    u16*   zero  = (u16*)(W + 8421376);              //  .. 8,421,888  (1024 u16)
    int*   adj   = (int*)(W + 8421888);              //  .. 8,684,032  (NN*MAXD ints)
    float* wadj  = W + 8684032;                      //  .. 8,946,176  (NN*MAXD)
    int*   cnt   = (int*)(W + 8946176);              //  .. 8,948,224  (NN ints)
    int*   oadj  = (int*)(W + 8948224);              //  .. 9,210,368  (NN*MAXD ints)
    int*   ocnt  = (int*)(W + 9210368);              //  .. 9,212,416  (NN ints)
    int*   iadj  = (int*)(W + 9212416);              //  .. 9,474,560  (NN*MAXD ints)
    int*   icnt  = (int*)(W + 9474560);              //  .. 9,476,608  (NN ints)
    u16*   ctxb  = (u16*)(W + 9476608);              //  .. 10,000,896 (NN*DND u16)
    u16*   xupdb = (u16*)(W + 10000896);             //  .. 10,525,184 (NN*DND u16)
    u16*   sums  = (u16*)(W + 10525184);             //  .. 11,049,472 (NN*DND u16)
    u16*   nfb   = (u16*)(W + 11049472);             //  .. 11,573,760 (NN*DND u16)
    u16*   wbf   = (u16*)(W + 11573760);             //  .. 14,457,344 (5,767,168 u16)
    u16*   efbA  = (u16*)(W + 14457344);             //  .. 22,845,952 (EE*DND u16)
    u16*   efbB  = (u16*)(W + 22845952);             //  .. 31,234,560 (EE*DND u16)
    int*   table = (int*)efbA;                       //  alias: setup-only (16.8 MB < 33.5 MB)
    // total: 31,234,560 floats = 124.9 MB

    u16* inwb = wbf;
    u16* owb  = wbf + 1572864;
    u16* etwb = wbf + 2097152;
    u16* unwb = wbf + 2621440;
    u16* uewb = wbf + 3670016;

    float* out_nf = (float*)d_out;
    float* out_ef = out_nf + (size_t)NN * DND;

    const int* srcv = ei;
    const int* dstv = ei + EE;

    const u16* WSu = (const u16*)d_ws;
    auto uoff = [&](const void* p) { return (u32)((const u16*)p - WSu); };

    // setup: edge table, reverse-edge index, attention CSR, edge-id CSRs
    init_table_k<<<NN * NN / 256, 256, 0, stream>>>(table);
    fill_table_k<<<EE / 256, 256, 0, stream>>>(ei, table);
    build_rev_k<<<EE / 256, 256, 0, stream>>>(ei, table, rev);
    init_csr_k<<<NN / 256, 256, 0, stream>>>(adj, wadj, cnt);
    fill_csr_k<<<EE / 256, 256, 0, stream>>>(ei, rev, pos, adj, wadj, cnt);
    init_ecsr_k<<<NN / 256, 256, 0, stream>>>(ocnt, icnt);
    fill_ecsr_k<<<EE / 256, 256, 0, stream>>>(ei, oadj, ocnt, iadj, icnt);
    hipMemsetAsync(zero, 0, 2048, stream);

    // bf16 weight copies (both layers at once)
    conv_k<<<1572864 / 2048, 256, 0, stream>>>(inw, inwb);
    conv_k<<<524288 / 2048, 256, 0, stream>>>(ow, owb);
    conv_k<<<524288 / 2048, 256, 0, stream>>>(etw, etwb);
    conv_k<<<1048576 / 2048, 256, 0, stream>>>(unw, unwb);
    conv_k<<<2097152 / 2048, 256, 0, stream>>>(uew, uewb);
    // bf16 activations for layer 0
    conv_k<<<1048576 / 2048, 256, 0, stream>>>(x, nfb);
    conv_k<<<16777216 / 2048, 256, 0, stream>>>(efin, efbA);

    for (int l = 0; l < 2; ++l) {
        const u16* efb_cur = l ? efbB : efbA;
        const u16* inwb_l = inwb + (size_t)l * 786432;
        const u16* owb_l  = owb  + (size_t)l * 262144;
        const u16* etwb_l = etwb + (size_t)l * 262144;
        const u16* unwb_l = unwb + (size_t)l * 524288;
        const u16* uewb_l = uewb + (size_t)l * 1048576;
        const float* inb_l  = inb  + (size_t)l * 1536;
        const float* ob_l   = ob   + (size_t)l * 512;
        const float* etb_l  = etb  + (size_t)l * 512;
        const float* etg_l  = etg  + (size_t)l * 512;
        const float* etbb_l = etbb + (size_t)l * 512;
        const float* unb_l  = unb  + (size_t)l * 512;
        const float* ueb_l  = ueb  + (size_t)l * 512;

        // qkv = nf @ inw^T + inb   (f32 out for attention; qkv region free: te not yet written)
        mgemm_k<0, 0, 1, 0, 12><<<192, 256, 0, stream>>>(
            WSu, uoff(nfb), uoff(inwb_l), inb_l, qkv, nullptr, NN, 3 * DND, DND,
            0, 0, 0, nullptr, nullptr, nullptr, nullptr, nullptr);

        // sparse masked MHSA -> ctx (bf16)
        attn_sp_k<<<dim3(NN, 2), 256, 0, stream>>>(qkv, adj, wadj, cnt, ctxb);

        // x_upd = ctx @ ow^T + ob  (bf16 out, only consumed by update_node gather)
        mgemm_k<0, 0, 0, 1, 4><<<64, 256, 0, stream>>>(
            WSu, uoff(ctxb), uoff(owb_l), ob_l, nullptr, xupdb, NN, DND, DND,
            0, 0, 0, nullptr, nullptr, nullptr, nullptr, nullptr);

        // te = relu(BN(ef @ etw^T + etb))  (bf16, coalesced; overwrites dead qkv)
        mgemm_k<0, 2, 0, 1, 4><<<1024, 256, 0, stream>>>(
            WSu, uoff(efb_cur), uoff(etwb_l), etb_l, nullptr, te, EE, DND, DND,
            0, 0, 0, nullptr, nullptr, nullptr, etg_l, etbb_l);

        // sums = bf16(max_out te + max_in te)   (replaces atomics + memset + sumso)
        gather_max_k<<<NN, 256, 0, stream>>>(te, oadj, ocnt, iadj, icnt, sums);

        // ef_next = (relu?)([nf[src], ef, ef[rev], nf[dst]] @ uew^T + ueb)
        if (l == 0)
            mgemm_k<1, 1, 0, 1, 4><<<1024, 256, 0, stream>>>(
                WSu, 0, uoff(uewb_l), ueb_l, nullptr, efbB, EE, DND, 2048,
                uoff(nfb), uoff(efb_cur), uoff(zero), srcv, dstv, rev, nullptr, nullptr);
        else
            mgemm_k<1, 0, 1, 0, 4><<<1024, 256, 0, stream>>>(
                WSu, 0, uoff(uewb_l), ueb_l, out_ef, nullptr, EE, DND, 2048,
                uoff(nfb), uoff(efb_cur), uoff(zero), srcv, dstv, rev, nullptr, nullptr);

        // nf_next = (relu?)([x_upd, subj+obj] @ unw^T + unb)
        if (l == 0)
            mgemm_k<2, 1, 0, 1, 4><<<64, 256, 0, stream>>>(
                WSu, 0, uoff(unwb_l), unb_l, nullptr, nfb, NN, DND, 1024,
                uoff(xupdb), uoff(sums), 0, nullptr, nullptr, nullptr, nullptr, nullptr);
        else
            mgemm_k<2, 0, 1, 0, 4><<<64, 256, 0, stream>>>(
                WSu, 0, uoff(unwb_l), unb_l, out_nf, nullptr, NN, DND, 1024,
                uoff(xupdb), uoff(sums), 0, nullptr, nullptr, nullptr, nullptr, nullptr);
    }
}